// Round 2
// baseline (2336.457 us; speedup 1.0000x reference)
//
#include <hip/hip_runtime.h>
#include <hip/hip_bf16.h>

#define B_ 4
#define S_ 2048
#define DM_ 512
#define H_ 4
#define DK_ 128
#define DI_ 1024
#define NV_ 5000

// ---------------- embed + temporal ----------------
__global__ __launch_bounds__(256) void embed_kernel(
    const int* __restrict__ et, const int* __restrict__ vx,
    const float* __restrict__ tmv, const float* __restrict__ npm,
    const float* __restrict__ eemb, const float* __restrict__ vemb,
    float* __restrict__ enc0) {
  int row = blockIdx.x;              // b*S + s
  int t = et[row], v = vx[row];
  float time = tmv[row], mask = npm[row];
  int tid = threadIdx.x;
  #pragma unroll
  for (int k = 0; k < 2; ++k) {
    int dd = tid + k * 256;
    float pv = powf(10000.0f, (float)(dd & ~1) / 512.0f);
    float r = time / pv;
    float tem = (((dd & 1) == 0) ? sinf(r) : cosf(r)) * mask;
    enc0[(size_t)row * DM_ + dd] =
        eemb[(size_t)t * DM_ + dd] + vemb[(size_t)v * DM_ + dd] + tem;
  }
}

// ---------------- similarity ----------------
__global__ __launch_bounds__(256) void sim_kernel(
    const int* __restrict__ vx, const float* __restrict__ A,
    const float* __restrict__ W, float* __restrict__ sim) {
  int i = blockIdx.x;
  int b = blockIdx.y;
  int vi = vx[b * S_ + i];
  float* out = sim + ((size_t)(b * S_ + i)) * S_;
  if (vi == 0) {
    for (int j = threadIdx.x; j < S_; j += 256) out[j] = 0.f;
    return;
  }
  const float* Arow = A + (size_t)(vi - 1) * NV_;
  const float* Wrow = W + (size_t)(vi - 1) * NV_;
  for (int j = threadIdx.x; j < S_; j += 256) {
    int vj = vx[b * S_ + j];
    out[j] = vj ? Arow[vj - 1] * Wrow[vj - 1] * 10.0f : 0.f;
  }
}

// ---------------- f32 tiled GEMM: C = A[M,K] @ B[K,N] (+bias)(+relu) ----------------
template <bool RELU>
__global__ __launch_bounds__(256) void gemm_kernel(
    const float* __restrict__ A, const float* __restrict__ Bm,
    const float* __restrict__ bias, float* __restrict__ C,
    int M, int N, int K) {
  __shared__ float As[16][64];
  __shared__ float Bs[16][68];
  int tid = threadIdx.x;
  int tx = tid & 15, ty = tid >> 4;
  int row0 = blockIdx.y * 64, col0 = blockIdx.x * 64;
  float acc[4][4] = {};
  for (int k0 = 0; k0 < K; k0 += 16) {
    {
      int r = tid >> 2, c = (tid & 3) * 4;
      float4 a4 = *(const float4*)&A[(size_t)(row0 + r) * K + k0 + c];
      As[c + 0][r] = a4.x; As[c + 1][r] = a4.y;
      As[c + 2][r] = a4.z; As[c + 3][r] = a4.w;
      int rb = tid >> 4, cb = (tid & 15) * 4;
      *(float4*)&Bs[rb][cb] = *(const float4*)&Bm[(size_t)(k0 + rb) * N + col0 + cb];
    }
    __syncthreads();
    #pragma unroll
    for (int k = 0; k < 16; ++k) {
      float a[4], bv[4];
      *(float4*)a = *(float4*)&As[k][ty * 4];
      *(float4*)bv = *(float4*)&Bs[k][tx * 4];
      #pragma unroll
      for (int i = 0; i < 4; ++i)
        #pragma unroll
        for (int j = 0; j < 4; ++j)
          acc[i][j] += a[i] * bv[j];
    }
    __syncthreads();
  }
  #pragma unroll
  for (int i = 0; i < 4; ++i) {
    int r = row0 + ty * 4 + i;
    #pragma unroll
    for (int j = 0; j < 4; ++j) {
      int cc = col0 + tx * 4 + j;
      float v = acc[i][j] + (bias ? bias[cc] : 0.f);
      if (RELU) v = fmaxf(v, 0.f);
      C[(size_t)r * N + cc] = v;
    }
  }
}

// ---------------- flash attention with sim bias + pad/causal mask ----------------
#define TQ 32
#define TK 32
__global__ __launch_bounds__(256) void attn_kernel(
    const float* __restrict__ Q, const float* __restrict__ Kb,
    const float* __restrict__ Vb, const float* __restrict__ sim,
    const int* __restrict__ et, float* __restrict__ O) {
  __shared__ float Qs[TQ][132];
  __shared__ float Ks[TK][132];
  __shared__ float Vs[TK][132];
  __shared__ float Ps[TQ][TK + 1];
  int b = blockIdx.z, h = blockIdx.y, i0 = blockIdx.x * TQ;
  int tid = threadIdx.x;
  for (int idx = tid; idx < TQ * 32; idx += 256) {
    int r = idx >> 5, c = idx & 31;
    *(float4*)&Qs[r][c * 4] =
        *(const float4*)&Q[((size_t)(b * S_ + i0 + r)) * DM_ + h * DK_ + c * 4];
  }
  int qi = tid >> 3;   // 0..31 query row in tile
  int l8 = tid & 7;    // 0..7 lane within row-group
  int gi = i0 + qi;
  float m = -INFINITY, l = 0.f;
  float o[16];
  #pragma unroll
  for (int c = 0; c < 16; ++c) o[c] = 0.f;

  for (int j0 = 0; j0 < S_; j0 += TK) {
    __syncthreads();
    for (int idx = tid; idx < TK * 32; idx += 256) {
      int r = idx >> 5, c = idx & 31;
      size_t g = ((size_t)(b * S_ + j0 + r)) * DM_ + h * DK_ + c * 4;
      *(float4*)&Ks[r][c * 4] = *(const float4*)&Kb[g];
      *(float4*)&Vs[r][c * 4] = *(const float4*)&Vb[g];
    }
    __syncthreads();
    float s[4];
    #pragma unroll
    for (int jj = 0; jj < 4; ++jj) {
      int kj = l8 + 8 * jj;
      int gj = j0 + kj;
      float acc = 0.f;
      #pragma unroll
      for (int c = 0; c < 32; ++c) {
        float4 q4 = *(float4*)&Qs[qi][c * 4];
        float4 k4 = *(float4*)&Ks[kj][c * 4];
        acc += q4.x * k4.x + q4.y * k4.y + q4.z * k4.z + q4.w * k4.w;
      }
      bool masked = (gj > gi) || (et[b * S_ + gj] == 0);
      s[jj] = masked ? -1e9f
                     : (acc * 0.08838834764831845f +
                        sim[((size_t)(b * S_) + gi) * S_ + gj]);
    }
    float tmax = fmaxf(fmaxf(s[0], s[1]), fmaxf(s[2], s[3]));
    tmax = fmaxf(tmax, __shfl_xor(tmax, 1, 8));
    tmax = fmaxf(tmax, __shfl_xor(tmax, 2, 8));
    tmax = fmaxf(tmax, __shfl_xor(tmax, 4, 8));
    float mn = fmaxf(m, tmax);
    float alpha = __expf(m - mn);
    float ts = 0.f;
    #pragma unroll
    for (int jj = 0; jj < 4; ++jj) {
      float p = __expf(s[jj] - mn);
      Ps[qi][l8 + 8 * jj] = p;
      ts += p;
    }
    ts += __shfl_xor(ts, 1, 8);
    ts += __shfl_xor(ts, 2, 8);
    ts += __shfl_xor(ts, 4, 8);
    l = l * alpha + ts;
    m = mn;
    __syncthreads();
    #pragma unroll
    for (int c = 0; c < 16; ++c) o[c] *= alpha;
    for (int k = 0; k < TK; ++k) {
      float p = Ps[qi][k];
      #pragma unroll
      for (int c = 0; c < 4; ++c) {
        float4 v4 = *(float4*)&Vs[k][l8 * 4 + 32 * c];
        o[c * 4 + 0] += p * v4.x;
        o[c * 4 + 1] += p * v4.y;
        o[c * 4 + 2] += p * v4.z;
        o[c * 4 + 3] += p * v4.w;
      }
    }
  }
  float inv = 1.f / l;
  #pragma unroll
  for (int c = 0; c < 4; ++c) {
    float4 r;
    r.x = o[c * 4 + 0] * inv; r.y = o[c * 4 + 1] * inv;
    r.z = o[c * 4 + 2] * inv; r.w = o[c * 4 + 3] * inv;
    *(float4*)&O[((size_t)(b * S_ + gi)) * DM_ + h * DK_ + l8 * 4 + 32 * c] = r;
  }
}

// ---------------- layernorm((x + res)) * g + b, * npm ----------------
__global__ __launch_bounds__(256) void ln_kernel(
    const float* __restrict__ x, const float* __restrict__ res,
    const float* __restrict__ g, const float* __restrict__ bta,
    const float* __restrict__ npm, float* __restrict__ out) {
  __shared__ float ssum[4], ssq[4];
  int row = blockIdx.x;
  int tid = threadIdx.x;
  size_t base = (size_t)row * DM_;
  float v0 = x[base + tid] + res[base + tid];
  float v1 = x[base + tid + 256] + res[base + tid + 256];
  float sum = v0 + v1, sq = v0 * v0 + v1 * v1;
  #pragma unroll
  for (int off = 32; off >= 1; off >>= 1) {
    sum += __shfl_down(sum, off);
    sq += __shfl_down(sq, off);
  }
  int wid = tid >> 6, lane = tid & 63;
  if (lane == 0) { ssum[wid] = sum; ssq[wid] = sq; }
  __syncthreads();
  sum = ssum[0] + ssum[1] + ssum[2] + ssum[3];
  sq = ssq[0] + ssq[1] + ssq[2] + ssq[3];
  float mean = sum * (1.f / DM_);
  float var = sq * (1.f / DM_) - mean * mean;
  float rs = rsqrtf(var + 1e-5f);
  float mask = npm[row];
  out[base + tid] = ((v0 - mean) * rs * g[tid] + bta[tid]) * mask;
  out[base + tid + 256] =
      ((v1 - mean) * rs * g[tid + 256] + bta[tid + 256]) * mask;
}

extern "C" void kernel_launch(void* const* d_in, const int* in_sizes, int n_in,
                              void* d_out, int out_size, void* d_ws,
                              size_t ws_size, hipStream_t stream) {
  const int* et = (const int*)d_in[0];
  const int* vx = (const int*)d_in[1];
  const float* tmv = (const float*)d_in[2];
  const float* npm = (const float*)d_in[3];
  const float* Amat = (const float*)d_in[4];
  const float* Wmat = (const float*)d_in[5];
  const float* eemb = (const float*)d_in[6];
  const float* vemb = (const float*)d_in[7];
  const float* Wq = (const float*)d_in[8];
  const float* Wk = (const float*)d_in[9];
  const float* Wv = (const float*)d_in[10];
  const float* Wo = (const float*)d_in[11];
  const float* bo = (const float*)d_in[12];
  const float* ln1g = (const float*)d_in[13];
  const float* ln1b = (const float*)d_in[14];
  const float* w1 = (const float*)d_in[15];
  const float* b1 = (const float*)d_in[16];
  const float* w2 = (const float*)d_in[17];
  const float* b2 = (const float*)d_in[18];
  const float* ln2g = (const float*)d_in[19];
  const float* ln2b = (const float*)d_in[20];

  float* out = (float*)d_out;
  float* enc_out = out;                      // [B,S,DM]
  float* sim_out = out + (size_t)B_ * S_ * DM_;  // [B,1,S,S]

  float* ws = (float*)d_ws;
  const size_t RSZ = (size_t)B_ * S_ * DM_;  // 4,194,304 floats
  float* enc0 = ws;            // 0
  float* Qb = ws + RSZ;        // 1
  float* Kbuf = ws + 2 * RSZ;  // 2
  float* Vbuf = ws + 3 * RSZ;  // 3
  float* Ob = ws + 4 * RSZ;    // 4
  float* OP = Qb;              // reuse (Q dead after attention)
  float* enc1 = Kbuf;          // reuse (K dead after attention)
  float* hid = Vbuf;           // spans slots 3..4 (V,O dead after proj)
  float* fbuf = enc0;          // reuse (enc0 dead after LN1)

  int M = B_ * S_;

  embed_kernel<<<dim3(M), dim3(256), 0, stream>>>(et, vx, tmv, npm, eemb, vemb, enc0);
  sim_kernel<<<dim3(S_, B_), dim3(256), 0, stream>>>(vx, Amat, Wmat, sim_out);

  gemm_kernel<false><<<dim3(DM_ / 64, M / 64), dim3(256), 0, stream>>>(
      enc0, Wq, nullptr, Qb, M, DM_, DM_);
  gemm_kernel<false><<<dim3(DM_ / 64, M / 64), dim3(256), 0, stream>>>(
      enc0, Wk, nullptr, Kbuf, M, DM_, DM_);
  gemm_kernel<false><<<dim3(DM_ / 64, M / 64), dim3(256), 0, stream>>>(
      enc0, Wv, nullptr, Vbuf, M, DM_, DM_);

  attn_kernel<<<dim3(S_ / TQ, H_, B_), dim3(256), 0, stream>>>(
      Qb, Kbuf, Vbuf, sim_out, et, Ob);

  gemm_kernel<false><<<dim3(DM_ / 64, M / 64), dim3(256), 0, stream>>>(
      Ob, Wo, bo, OP, M, DM_, DM_);
  ln_kernel<<<dim3(M), dim3(256), 0, stream>>>(OP, enc0, ln1g, ln1b, npm, enc1);

  gemm_kernel<true><<<dim3(DI_ / 64, M / 64), dim3(256), 0, stream>>>(
      enc1, w1, b1, hid, M, DI_, DM_);
  gemm_kernel<false><<<dim3(DM_ / 64, M / 64), dim3(256), 0, stream>>>(
      hid, w2, b2, fbuf, M, DM_, DI_);
  ln_kernel<<<dim3(M), dim3(256), 0, stream>>>(fbuf, enc1, ln2g, ln2b, npm, enc_out);
}

// Round 4
// 1036.592 us; speedup vs baseline: 2.2540x; 2.2540x over previous
//
#include <hip/hip_runtime.h>
#include <hip/hip_bf16.h>

#define B_ 4
#define S_ 2048
#define DM_ 512
#define H_ 4
#define DK_ 128
#define DI_ 1024
#define NV_ 5000

typedef __attribute__((ext_vector_type(8))) short bf16x8;
typedef __attribute__((ext_vector_type(8))) unsigned short u16x8;
typedef __attribute__((ext_vector_type(4))) float f32x4;

__device__ inline unsigned short f2bf(float x) {
  unsigned int u = __float_as_uint(x);
  unsigned int r = (u + 0x7fffu + ((u >> 16) & 1u)) >> 16;
  return (unsigned short)r;
}

// ---------------- embed + temporal ----------------
__global__ __launch_bounds__(256) void embed_kernel(
    const int* __restrict__ et, const int* __restrict__ vx,
    const float* __restrict__ tmv, const float* __restrict__ npm,
    const float* __restrict__ eemb, const float* __restrict__ vemb,
    float* __restrict__ enc0) {
  int row = blockIdx.x;
  int t = et[row], v = vx[row];
  float time = tmv[row], mask = npm[row];
  int tid = threadIdx.x;
  #pragma unroll
  for (int k = 0; k < 2; ++k) {
    int dd = tid + k * 256;
    float pv = powf(10000.0f, (float)(dd & ~1) / 512.0f);
    float r = time / pv;
    float tem = (((dd & 1) == 0) ? sinf(r) : cosf(r)) * mask;
    enc0[(size_t)row * DM_ + dd] =
        eemb[(size_t)t * DM_ + dd] + vemb[(size_t)v * DM_ + dd] + tem;
  }
}

// ---------------- similarity ----------------
__global__ __launch_bounds__(256) void sim_kernel(
    const int* __restrict__ vx, const float* __restrict__ A,
    const float* __restrict__ W, float* __restrict__ sim) {
  int i = blockIdx.x;
  int b = blockIdx.y;
  int vi = vx[b * S_ + i];
  float* out = sim + ((size_t)(b * S_ + i)) * S_;
  if (vi == 0) {
    for (int j = threadIdx.x; j < S_; j += 256) out[j] = 0.f;
    return;
  }
  const float* Arow = A + (size_t)(vi - 1) * NV_;
  const float* Wrow = W + (size_t)(vi - 1) * NV_;
  for (int j = threadIdx.x; j < S_; j += 256) {
    int vj = vx[b * S_ + j];
    out[j] = vj ? Arow[vj - 1] * Wrow[vj - 1] * 10.0f : 0.f;
  }
}

// ---------------- f32 tiled GEMM (unchanged) ----------------
template <bool RELU>
__global__ __launch_bounds__(256) void gemm_kernel(
    const float* __restrict__ A, const float* __restrict__ Bm,
    const float* __restrict__ bias, float* __restrict__ C,
    int M, int N, int K) {
  __shared__ float As[16][64];
  __shared__ float Bs[16][68];
  int tid = threadIdx.x;
  int tx = tid & 15, ty = tid >> 4;
  int row0 = blockIdx.y * 64, col0 = blockIdx.x * 64;
  float acc[4][4] = {};
  for (int k0 = 0; k0 < K; k0 += 16) {
    {
      int r = tid >> 2, c = (tid & 3) * 4;
      float4 a4 = *(const float4*)&A[(size_t)(row0 + r) * K + k0 + c];
      As[c + 0][r] = a4.x; As[c + 1][r] = a4.y;
      As[c + 2][r] = a4.z; As[c + 3][r] = a4.w;
      int rb = tid >> 4, cb = (tid & 15) * 4;
      *(float4*)&Bs[rb][cb] = *(const float4*)&Bm[(size_t)(k0 + rb) * N + col0 + cb];
    }
    __syncthreads();
    #pragma unroll
    for (int k = 0; k < 16; ++k) {
      float a[4], bv[4];
      *(float4*)a = *(float4*)&As[k][ty * 4];
      *(float4*)bv = *(float4*)&Bs[k][tx * 4];
      #pragma unroll
      for (int i = 0; i < 4; ++i)
        #pragma unroll
        for (int j = 0; j < 4; ++j)
          acc[i][j] += a[i] * bv[j];
    }
    __syncthreads();
  }
  #pragma unroll
  for (int i = 0; i < 4; ++i) {
    int r = row0 + ty * 4 + i;
    #pragma unroll
    for (int j = 0; j < 4; ++j) {
      int cc = col0 + tx * 4 + j;
      float v = acc[i][j] + (bias ? bias[cc] : 0.f);
      if (RELU) v = fmaxf(v, 0.f);
      C[(size_t)r * N + cc] = v;
    }
  }
}

// ---------------- prep: Q,K f32 [b][s][h*128+d] -> bf16 [b*H+h][s][d] ----------------
__global__ __launch_bounds__(256) void prep_qk_kernel(
    const float* __restrict__ Qf, const float* __restrict__ Kf,
    unsigned short* __restrict__ Qb, unsigned short* __restrict__ Kb) {
  int gid = blockIdx.x * 256 + threadIdx.x;  // [0, 524288)
  int e0 = gid * 8;
  int row = e0 >> 9;     // b*S + s
  int wr = e0 & 511;
  int h = wr >> 7, d = wr & 127;
  int b = row >> 11, s = row & 2047;
  size_t src = (size_t)row * 512 + wr;
  size_t dst = ((size_t)((b * 4 + h) * 2048 + s)) * 128 + d;
  {
    float4 a = *(const float4*)&Qf[src];
    float4 c = *(const float4*)&Qf[src + 4];
    u16x8 o;
    o[0] = f2bf(a.x); o[1] = f2bf(a.y); o[2] = f2bf(a.z); o[3] = f2bf(a.w);
    o[4] = f2bf(c.x); o[5] = f2bf(c.y); o[6] = f2bf(c.z); o[7] = f2bf(c.w);
    *(u16x8*)&Qb[dst] = o;
  }
  {
    float4 a = *(const float4*)&Kf[src];
    float4 c = *(const float4*)&Kf[src + 4];
    u16x8 o;
    o[0] = f2bf(a.x); o[1] = f2bf(a.y); o[2] = f2bf(a.z); o[3] = f2bf(a.w);
    o[4] = f2bf(c.x); o[5] = f2bf(c.y); o[6] = f2bf(c.z); o[7] = f2bf(c.w);
    *(u16x8*)&Kb[dst] = o;
  }
}

// ---------------- prep: V f32 -> bf16 transposed [b*H+h][dv][s] ----------------
__global__ __launch_bounds__(256) void prep_v_kernel(
    const float* __restrict__ Vf, unsigned short* __restrict__ Vt) {
  __shared__ __attribute__((aligned(16))) unsigned short T[64][72];
  int blk = blockIdx.x;      // 1024
  int bh = blk >> 6;
  int rem = blk & 63;
  int s0 = (rem >> 1) * 64;
  int d0 = (rem & 1) * 64;
  int b = bh >> 2, h = bh & 3;
  int tid = threadIdx.x;
  int r = tid >> 2, cb = (tid & 3) * 16;
  const float* src = Vf + ((size_t)(b * 2048 + s0 + r)) * 512 + h * 128 + d0 + cb;
  #pragma unroll
  for (int k = 0; k < 16; k += 4) {
    float4 v4 = *(const float4*)&src[k];
    T[r][cb + k + 0] = f2bf(v4.x);
    T[r][cb + k + 1] = f2bf(v4.y);
    T[r][cb + k + 2] = f2bf(v4.z);
    T[r][cb + k + 3] = f2bf(v4.w);
  }
  __syncthreads();
  unsigned short* dst = Vt + ((size_t)(bh * 128 + d0 + r)) * 2048 + s0 + cb;
  u16x8 o0, o1;
  #pragma unroll
  for (int k = 0; k < 8; ++k) o0[k] = T[cb + k][r];
  #pragma unroll
  for (int k = 0; k < 8; ++k) o1[k] = T[cb + 8 + k][r];
  *(u16x8*)&dst[0] = o0;
  *(u16x8*)&dst[8] = o1;
}

// ---------------- MFMA flash attention, causal tile skip ----------------
// block = 256 (4 waves), per block: 64 q-rows (16/wave), kv tiles of 64
__global__ __launch_bounds__(256) void attn_mfma_kernel(
    const unsigned short* __restrict__ Qb, const unsigned short* __restrict__ Kb,
    const unsigned short* __restrict__ Vt, const float* __restrict__ sim,
    const float* __restrict__ npm, float* __restrict__ O) {
  __shared__ __attribute__((aligned(16))) unsigned short Ks[64][136];
  __shared__ __attribute__((aligned(16))) unsigned short Vts[128][72];
  __shared__ __attribute__((aligned(16))) unsigned short Pl[4][16][72];
  __shared__ float sims[64][64];
  __shared__ float mskf[64];
  int bid = blockIdx.x;
  int qt = 31 - (bid & 31);  // heavy tiles first
  int bh = bid >> 5;         // b*H + h
  int b = bh >> 2;
  int h = bh & 3;
  int tid = threadIdx.x;
  int w = tid >> 6, l = tid & 63;
  int l16 = l & 15, lh = l >> 4;
  int q0 = qt * 64 + w * 16;

  // Q fragments (A-frag: row = l&15, k = lh*8+j within 32-chunk kc)
  bf16x8 qf[4];
  const unsigned short* Qrow = Qb + ((size_t)(bh * 2048 + q0 + l16)) * 128;
  #pragma unroll
  for (int kc = 0; kc < 4; ++kc)
    qf[kc] = *(const bf16x8*)&Qrow[kc * 32 + lh * 8];

  float m_r[4], l_r[4];
  f32x4 o_acc[8];
  #pragma unroll
  for (int r = 0; r < 4; ++r) { m_r[r] = -INFINITY; l_r[r] = 0.f; }
  #pragma unroll
  for (int c = 0; c < 8; ++c) o_acc[c] = (f32x4){0.f, 0.f, 0.f, 0.f};

  for (int t = 0; t <= qt; ++t) {
    int kv0 = t * 64;
    __syncthreads();
    // stage K tile [64][128]
    for (int it = tid; it < 1024; it += 256) {
      int r = it >> 4, c = it & 15;
      *(uint4*)&Ks[r][c * 8] =
          *(const uint4*)&Kb[((size_t)(bh * 2048 + kv0 + r)) * 128 + c * 8];
    }
    // stage Vt tile [128][64]
    for (int it = tid; it < 1024; it += 256) {
      int r = it >> 3, c = it & 7;
      *(uint4*)&Vts[r][c * 8] =
          *(const uint4*)&Vt[((size_t)(bh * 128 + r)) * 2048 + kv0 + c * 8];
    }
    // stage sim tile [64 q][64 kv] (f32)
    for (int it = tid; it < 1024; it += 256) {
      int r = it >> 4, c = it & 15;
      *(float4*)&sims[r][c * 4] =
          *(const float4*)&sim[((size_t)(b * 2048) + qt * 64 + r) * 2048 + kv0 + c * 4];
    }
    if (tid < 64) mskf[tid] = npm[b * 2048 + kv0 + tid];
    __syncthreads();

    // QK^T: 4 C-tiles of 16x16 (kv chunks), depth 128
    f32x4 sc[4];
    #pragma unroll
    for (int tt = 0; tt < 4; ++tt) {
      sc[tt] = (f32x4){0.f, 0.f, 0.f, 0.f};
      #pragma unroll
      for (int kc = 0; kc < 4; ++kc) {
        bf16x8 kf = *(bf16x8*)&Ks[tt * 16 + l16][kc * 32 + lh * 8];
        sc[tt] = __builtin_amdgcn_mfma_f32_16x16x32_bf16(qf[kc], kf, sc[tt], 0, 0, 0);
      }
    }
    // mask + bias  (C layout: row q = lh*4+r, col kv = l16)
    float sv[4][4];
    #pragma unroll
    for (int tt = 0; tt < 4; ++tt) {
      int kvl = tt * 16 + l16;
      int kvg = kv0 + kvl;
      float msk = mskf[kvl];
      #pragma unroll
      for (int r = 0; r < 4; ++r) {
        int qg = q0 + lh * 4 + r;
        bool valid = (kvg <= qg) && (msk != 0.f);
        sv[tt][r] = valid
            ? sc[tt][r] * 0.08838834764831845f + sims[w * 16 + lh * 4 + r][kvl]
            : -1e9f;
      }
    }
    // online softmax per row (16-lane groups share a row)
    #pragma unroll
    for (int r = 0; r < 4; ++r) {
      float mx = fmaxf(fmaxf(sv[0][r], sv[1][r]), fmaxf(sv[2][r], sv[3][r]));
      mx = fmaxf(mx, __shfl_xor(mx, 1));
      mx = fmaxf(mx, __shfl_xor(mx, 2));
      mx = fmaxf(mx, __shfl_xor(mx, 4));
      mx = fmaxf(mx, __shfl_xor(mx, 8));
      float mn = fmaxf(m_r[r], mx);
      float alpha = __expf(m_r[r] - mn);
      m_r[r] = mn;
      float ts = 0.f;
      #pragma unroll
      for (int tt = 0; tt < 4; ++tt) {
        float p = __expf(sv[tt][r] - mn);
        sv[tt][r] = p;
        ts += p;
      }
      ts += __shfl_xor(ts, 1);
      ts += __shfl_xor(ts, 2);
      ts += __shfl_xor(ts, 4);
      ts += __shfl_xor(ts, 8);
      l_r[r] = l_r[r] * alpha + ts;
      #pragma unroll
      for (int c = 0; c < 8; ++c) o_acc[c][r] *= alpha;
    }
    // P -> LDS (wave-private), C-layout scatter
    #pragma unroll
    for (int tt = 0; tt < 4; ++tt)
      #pragma unroll
      for (int r = 0; r < 4; ++r)
        Pl[w][lh * 4 + r][tt * 16 + l16] = f2bf(sv[tt][r]);
    // PV: O[16][128] += P[16][64] * V[64][128]
    #pragma unroll
    for (int kf2 = 0; kf2 < 2; ++kf2) {
      bf16x8 pa = *(bf16x8*)&Pl[w][l16][kf2 * 32 + lh * 8];
      #pragma unroll
      for (int c = 0; c < 8; ++c) {
        bf16x8 vf = *(bf16x8*)&Vts[c * 16 + l16][kf2 * 32 + lh * 8];
        o_acc[c] = __builtin_amdgcn_mfma_f32_16x16x32_bf16(pa, vf, o_acc[c], 0, 0, 0);
      }
    }
  }
  // epilogue
  #pragma unroll
  for (int r = 0; r < 4; ++r) {
    float inv = 1.f / l_r[r];
    int qg = q0 + lh * 4 + r;
    float* op = O + ((size_t)(b * 2048 + qg)) * 512 + h * 128;
    #pragma unroll
    for (int c = 0; c < 8; ++c) op[c * 16 + l16] = o_acc[c][r] * inv;
  }
}

// ---------------- layernorm ----------------
__global__ __launch_bounds__(256) void ln_kernel(
    const float* __restrict__ x, const float* __restrict__ res,
    const float* __restrict__ g, const float* __restrict__ bta,
    const float* __restrict__ npm, float* __restrict__ out) {
  __shared__ float ssum[4], ssq[4];
  int row = blockIdx.x;
  int tid = threadIdx.x;
  size_t base = (size_t)row * DM_;
  float v0 = x[base + tid] + res[base + tid];
  float v1 = x[base + tid + 256] + res[base + tid + 256];
  float sum = v0 + v1, sq = v0 * v0 + v1 * v1;
  #pragma unroll
  for (int off = 32; off >= 1; off >>= 1) {
    sum += __shfl_down(sum, off);
    sq += __shfl_down(sq, off);
  }
  int wid = tid >> 6, lane = tid & 63;
  if (lane == 0) { ssum[wid] = sum; ssq[wid] = sq; }
  __syncthreads();
  sum = ssum[0] + ssum[1] + ssum[2] + ssum[3];
  sq = ssq[0] + ssq[1] + ssq[2] + ssq[3];
  float mean = sum * (1.f / DM_);
  float var = sq * (1.f / DM_) - mean * mean;
  float rs = rsqrtf(var + 1e-5f);
  float mask = npm[row];
  out[base + tid] = ((v0 - mean) * rs * g[tid] + bta[tid]) * mask;
  out[base + tid + 256] =
      ((v1 - mean) * rs * g[tid + 256] + bta[tid + 256]) * mask;
}

extern "C" void kernel_launch(void* const* d_in, const int* in_sizes, int n_in,
                              void* d_out, int out_size, void* d_ws,
                              size_t ws_size, hipStream_t stream) {
  const int* et = (const int*)d_in[0];
  const int* vx = (const int*)d_in[1];
  const float* tmv = (const float*)d_in[2];
  const float* npm = (const float*)d_in[3];
  const float* Amat = (const float*)d_in[4];
  const float* Wmat = (const float*)d_in[5];
  const float* eemb = (const float*)d_in[6];
  const float* vemb = (const float*)d_in[7];
  const float* Wq = (const float*)d_in[8];
  const float* Wk = (const float*)d_in[9];
  const float* Wv = (const float*)d_in[10];
  const float* Wo = (const float*)d_in[11];
  const float* bo = (const float*)d_in[12];
  const float* ln1g = (const float*)d_in[13];
  const float* ln1b = (const float*)d_in[14];
  const float* w1 = (const float*)d_in[15];
  const float* b1 = (const float*)d_in[16];
  const float* w2 = (const float*)d_in[17];
  const float* b2 = (const float*)d_in[18];
  const float* ln2g = (const float*)d_in[19];
  const float* ln2b = (const float*)d_in[20];

  float* out = (float*)d_out;
  float* enc_out = out;
  float* sim_out = out + (size_t)B_ * S_ * DM_;

  float* ws = (float*)d_ws;
  const size_t RSZ = (size_t)B_ * S_ * DM_;  // 4,194,304 floats (16MB)
  float* enc0 = ws;                 // s0, live until LN1
  float* Qf = ws + RSZ;             // s1
  float* Kf = ws + 2 * RSZ;         // s2
  float* Vf = ws + 3 * RSZ;         // s3
  unsigned short* Qb16 = (unsigned short*)(ws + 4 * RSZ);        // s4 lower 8MB
  unsigned short* Kb16 = Qb16 + (size_t)B_ * H_ * S_ * DK_;      // s4 upper 8MB
  unsigned short* Vt16 = (unsigned short*)(ws + RSZ);            // s1 (Qf dead after prep_qk)
  float* Of = ws + 2 * RSZ;         // s2 (Kf dead after prep_qk)
  float* OP = ws + 3 * RSZ;         // s3 (Vf dead after prep_v)
  float* enc1 = ws + 4 * RSZ;       // s4 (bf16 dead after attn)
  float* hid = ws + RSZ;            // s1..s2 (32MB; Vt16/Of dead)
  float* fbuf = ws + 3 * RSZ;       // s3 (OP dead after LN1)

  int M = B_ * S_;

  embed_kernel<<<dim3(M), dim3(256), 0, stream>>>(et, vx, tmv, npm, eemb, vemb, enc0);
  sim_kernel<<<dim3(S_, B_), dim3(256), 0, stream>>>(vx, Amat, Wmat, sim_out);

  gemm_kernel<false><<<dim3(DM_ / 64, M / 64), dim3(256), 0, stream>>>(
      enc0, Wq, nullptr, Qf, M, DM_, DM_);
  gemm_kernel<false><<<dim3(DM_ / 64, M / 64), dim3(256), 0, stream>>>(
      enc0, Wk, nullptr, Kf, M, DM_, DM_);
  gemm_kernel<false><<<dim3(DM_ / 64, M / 64), dim3(256), 0, stream>>>(
      enc0, Wv, nullptr, Vf, M, DM_, DM_);

  prep_qk_kernel<<<dim3(2048), dim3(256), 0, stream>>>(Qf, Kf, Qb16, Kb16);
  prep_v_kernel<<<dim3(1024), dim3(256), 0, stream>>>(Vf, Vt16);

  attn_mfma_kernel<<<dim3(512), dim3(256), 0, stream>>>(
      Qb16, Kb16, Vt16, sim_out, npm, Of);

  gemm_kernel<false><<<dim3(DM_ / 64, M / 64), dim3(256), 0, stream>>>(
      Of, Wo, bo, OP, M, DM_, DM_);
  ln_kernel<<<dim3(M), dim3(256), 0, stream>>>(OP, enc0, ln1g, ln1b, npm, enc1);

  gemm_kernel<true><<<dim3(DI_ / 64, M / 64), dim3(256), 0, stream>>>(
      enc1, w1, b1, hid, M, DI_, DM_);
  gemm_kernel<false><<<dim3(DM_ / 64, M / 64), dim3(256), 0, stream>>>(
      hid, w2, b2, fbuf, M, DM_, DI_);
  ln_kernel<<<dim3(M), dim3(256), 0, stream>>>(fbuf, enc1, ln2g, ln2b, npm, enc_out);
}

// Round 5
// 515.248 us; speedup vs baseline: 4.5346x; 2.0118x over previous
//
#include <hip/hip_runtime.h>
#include <hip/hip_bf16.h>

#define B_ 4
#define S_ 2048
#define DM_ 512
#define H_ 4
#define DK_ 128
#define DI_ 1024
#define NV_ 5000

typedef __attribute__((ext_vector_type(8))) short bf16x8;
typedef __attribute__((ext_vector_type(8))) unsigned short u16x8;
typedef __attribute__((ext_vector_type(4))) unsigned short u16x4;
typedef __attribute__((ext_vector_type(4))) float f32x4;

__device__ inline unsigned short f2bf(float x) {
  unsigned int u = __float_as_uint(x);
  unsigned int r = (u + 0x7fffu + ((u >> 16) & 1u)) >> 16;
  return (unsigned short)r;
}

// ---------------- embed + temporal (f32 + bf16 outputs) ----------------
__global__ __launch_bounds__(256) void embed_kernel(
    const int* __restrict__ et, const int* __restrict__ vx,
    const float* __restrict__ tmv, const float* __restrict__ npm,
    const float* __restrict__ eemb, const float* __restrict__ vemb,
    float* __restrict__ enc0, unsigned short* __restrict__ enc0b) {
  int row = blockIdx.x;
  int t = et[row], v = vx[row];
  float time = tmv[row], mask = npm[row];
  int tid = threadIdx.x;
  #pragma unroll
  for (int k = 0; k < 2; ++k) {
    int dd = tid + k * 256;
    float pv = powf(10000.0f, (float)(dd & ~1) / 512.0f);
    float r = time / pv;
    float tem = (((dd & 1) == 0) ? sinf(r) : cosf(r)) * mask;
    float val = eemb[(size_t)t * DM_ + dd] + vemb[(size_t)v * DM_ + dd] + tem;
    enc0[(size_t)row * DM_ + dd] = val;
    enc0b[(size_t)row * DM_ + dd] = f2bf(val);
  }
}

// ---------------- AW precompute: AW = A*W*10 ----------------
__global__ __launch_bounds__(256) void aw_kernel(
    const float* __restrict__ A, const float* __restrict__ W,
    float* __restrict__ AW) {
  const size_t n4 = (size_t)NV_ * NV_ / 4;  // 6,250,000
  size_t stride = (size_t)gridDim.x * 256;
  for (size_t i = (size_t)blockIdx.x * 256 + threadIdx.x; i < n4; i += stride) {
    float4 a = ((const float4*)A)[i];
    float4 w = ((const float4*)W)[i];
    float4 o;
    o.x = a.x * w.x * 10.0f; o.y = a.y * w.y * 10.0f;
    o.z = a.z * w.z * 10.0f; o.w = a.w * w.w * 10.0f;
    ((float4*)AW)[i] = o;
  }
}

// ---------------- similarity from AW ----------------
__global__ __launch_bounds__(256) void sim2_kernel(
    const int* __restrict__ vx, const float* __restrict__ AW,
    float* __restrict__ sim) {
  int i = blockIdx.x;
  int b = blockIdx.y;
  int vi = vx[b * S_ + i];
  float* out = sim + ((size_t)(b * S_ + i)) * S_;
  if (vi == 0) {
    for (int j = threadIdx.x * 4; j < S_; j += 1024)
      *(float4*)&out[j] = (float4){0.f, 0.f, 0.f, 0.f};
    return;
  }
  const float* row = AW + (size_t)(vi - 1) * NV_;
  for (int j = threadIdx.x * 4; j < S_; j += 1024) {
    int4 vj = *(const int4*)&vx[b * S_ + j];
    float4 o;
    o.x = vj.x ? row[vj.x - 1] : 0.f;
    o.y = vj.y ? row[vj.y - 1] : 0.f;
    o.z = vj.z ? row[vj.z - 1] : 0.f;
    o.w = vj.w ? row[vj.w - 1] : 0.f;
    *(float4*)&out[j] = o;
  }
}

// ---------------- similarity fallback (direct A,W) ----------------
__global__ __launch_bounds__(256) void sim_kernel(
    const int* __restrict__ vx, const float* __restrict__ A,
    const float* __restrict__ W, float* __restrict__ sim) {
  int i = blockIdx.x;
  int b = blockIdx.y;
  int vi = vx[b * S_ + i];
  float* out = sim + ((size_t)(b * S_ + i)) * S_;
  if (vi == 0) {
    for (int j = threadIdx.x; j < S_; j += 256) out[j] = 0.f;
    return;
  }
  const float* Arow = A + (size_t)(vi - 1) * NV_;
  const float* Wrow = W + (size_t)(vi - 1) * NV_;
  for (int j = threadIdx.x; j < S_; j += 256) {
    int vj = vx[b * S_ + j];
    out[j] = vj ? Arow[vj - 1] * Wrow[vj - 1] * 10.0f : 0.f;
  }
}

// ---------------- weight transpose+cast: W[K][N] f32 -> WT[N][K] bf16 ----------------
__global__ __launch_bounds__(256) void wt_kernel(
    const float* __restrict__ W, unsigned short* __restrict__ WT,
    int K, int N) {
  __shared__ unsigned short T[32][40];
  int n0 = blockIdx.x * 32, k0 = blockIdx.y * 32;
  int r = threadIdx.x >> 3, c0 = (threadIdx.x & 7) * 4;
  float4 v = *(const float4*)&W[(size_t)(k0 + r) * N + n0 + c0];
  T[r][c0 + 0] = f2bf(v.x);
  T[r][c0 + 1] = f2bf(v.y);
  T[r][c0 + 2] = f2bf(v.z);
  T[r][c0 + 3] = f2bf(v.w);
  __syncthreads();
  u16x4 o;
  o[0] = T[c0 + 0][r]; o[1] = T[c0 + 1][r];
  o[2] = T[c0 + 2][r]; o[3] = T[c0 + 3][r];
  *(u16x4*)&WT[(size_t)(n0 + r) * K + k0 + c0] = o;
}

// ---------------- bf16 MFMA GEMM: C = A[M,K] @ BT[N,K]^T (+bias)(+relu) ----------------
// OMODE: 0 = f32 [M][N]; 1 = bf16 [M][N]; 2 = bf16 QK head-split; 3 = bf16 V-transposed
template <int OMODE, bool RELU>
__global__ __launch_bounds__(256) void gemm_bf16_kernel(
    const unsigned short* __restrict__ A, const unsigned short* __restrict__ BT,
    const float* __restrict__ bias, void* __restrict__ C,
    int M, int N, int K) {
  __shared__ __attribute__((aligned(16))) unsigned short As[128][72];
  __shared__ __attribute__((aligned(16))) unsigned short Bs[128][72];
  int tid = threadIdx.x;
  int w = tid >> 6, l = tid & 63;
  int l16 = l & 15, lh = l >> 4;
  int wr = w >> 1, wc = w & 1;
  int row0 = blockIdx.y * 128, col0 = blockIdx.x * 128;
  int ra = tid >> 1, ha = (tid & 1) * 32;
  f32x4 acc[4][4];
  #pragma unroll
  for (int m = 0; m < 4; ++m)
    #pragma unroll
    for (int n = 0; n < 4; ++n) acc[m][n] = (f32x4){0.f, 0.f, 0.f, 0.f};

  for (int k0 = 0; k0 < K; k0 += 64) {
    __syncthreads();
    {
      const unsigned short* sa = &A[(size_t)(row0 + ra) * K + k0 + ha];
      uint4 a0 = *(const uint4*)(sa);
      uint4 a1 = *(const uint4*)(sa + 8);
      uint4 a2 = *(const uint4*)(sa + 16);
      uint4 a3 = *(const uint4*)(sa + 24);
      *(uint4*)&As[ra][ha + 0] = a0;
      *(uint4*)&As[ra][ha + 8] = a1;
      *(uint4*)&As[ra][ha + 16] = a2;
      *(uint4*)&As[ra][ha + 24] = a3;
      const unsigned short* sb = &BT[(size_t)(col0 + ra) * K + k0 + ha];
      uint4 b0 = *(const uint4*)(sb);
      uint4 b1 = *(const uint4*)(sb + 8);
      uint4 b2 = *(const uint4*)(sb + 16);
      uint4 b3 = *(const uint4*)(sb + 24);
      *(uint4*)&Bs[ra][ha + 0] = b0;
      *(uint4*)&Bs[ra][ha + 8] = b1;
      *(uint4*)&Bs[ra][ha + 16] = b2;
      *(uint4*)&Bs[ra][ha + 24] = b3;
    }
    __syncthreads();
    #pragma unroll
    for (int kc = 0; kc < 2; ++kc) {
      bf16x8 af[4], bfr[4];
      #pragma unroll
      for (int m = 0; m < 4; ++m)
        af[m] = *(bf16x8*)&As[wr * 64 + m * 16 + l16][kc * 32 + lh * 8];
      #pragma unroll
      for (int n = 0; n < 4; ++n)
        bfr[n] = *(bf16x8*)&Bs[wc * 64 + n * 16 + l16][kc * 32 + lh * 8];
      #pragma unroll
      for (int m = 0; m < 4; ++m)
        #pragma unroll
        for (int n = 0; n < 4; ++n)
          acc[m][n] = __builtin_amdgcn_mfma_f32_16x16x32_bf16(af[m], bfr[n], acc[m][n], 0, 0, 0);
    }
  }
  // epilogue: C row = row0+wr*64+m*16+lh*4+r, col = col0+wc*64+n*16+l16
  #pragma unroll
  for (int m = 0; m < 4; ++m) {
    #pragma unroll
    for (int r = 0; r < 4; ++r) {
      int row = row0 + wr * 64 + m * 16 + lh * 4 + r;
      #pragma unroll
      for (int n = 0; n < 4; ++n) {
        int colg = col0 + wc * 64 + n * 16 + l16;
        float v = acc[m][n][r];
        if (bias) v += bias[colg];
        if (RELU) v = fmaxf(v, 0.f);
        if (OMODE == 0) {
          ((float*)C)[(size_t)row * N + colg] = v;
        } else if (OMODE == 1) {
          ((unsigned short*)C)[(size_t)row * N + colg] = f2bf(v);
        } else if (OMODE == 2) {
          int b = row >> 11, s = row & 2047;
          int h = colg >> 7, d = colg & 127;
          ((unsigned short*)C)[((size_t)((b * 4 + h) * 2048 + s)) * 128 + d] = f2bf(v);
        } else {
          int b = row >> 11, s = row & 2047;
          int h = colg >> 7, d = colg & 127;
          ((unsigned short*)C)[((size_t)((b * 4 + h) * 128 + d)) * 2048 + s] = f2bf(v);
        }
      }
    }
  }
}

// ---------------- MFMA flash attention, causal tile skip ----------------
__global__ __launch_bounds__(256) void attn_mfma_kernel(
    const unsigned short* __restrict__ Qb, const unsigned short* __restrict__ Kb,
    const unsigned short* __restrict__ Vt, const float* __restrict__ sim,
    const float* __restrict__ npm, unsigned short* __restrict__ O) {
  __shared__ __attribute__((aligned(16))) unsigned short Ks[64][136];
  __shared__ __attribute__((aligned(16))) unsigned short Vts[128][72];
  __shared__ __attribute__((aligned(16))) unsigned short Pl[4][16][72];
  __shared__ float sims[64][64];
  __shared__ float mskf[64];
  int bid = blockIdx.x;
  int qt = 31 - (bid & 31);
  int bh = bid >> 5;
  int b = bh >> 2;
  int h = bh & 3;
  int tid = threadIdx.x;
  int w = tid >> 6, l = tid & 63;
  int l16 = l & 15, lh = l >> 4;
  int q0 = qt * 64 + w * 16;

  bf16x8 qf[4];
  const unsigned short* Qrow = Qb + ((size_t)(bh * 2048 + q0 + l16)) * 128;
  #pragma unroll
  for (int kc = 0; kc < 4; ++kc)
    qf[kc] = *(const bf16x8*)&Qrow[kc * 32 + lh * 8];

  float m_r[4], l_r[4];
  f32x4 o_acc[8];
  #pragma unroll
  for (int r = 0; r < 4; ++r) { m_r[r] = -INFINITY; l_r[r] = 0.f; }
  #pragma unroll
  for (int c = 0; c < 8; ++c) o_acc[c] = (f32x4){0.f, 0.f, 0.f, 0.f};

  for (int t = 0; t <= qt; ++t) {
    int kv0 = t * 64;
    __syncthreads();
    for (int it = tid; it < 1024; it += 256) {
      int r = it >> 4, c = it & 15;
      *(uint4*)&Ks[r][c * 8] =
          *(const uint4*)&Kb[((size_t)(bh * 2048 + kv0 + r)) * 128 + c * 8];
    }
    for (int it = tid; it < 1024; it += 256) {
      int r = it >> 3, c = it & 7;
      *(uint4*)&Vts[r][c * 8] =
          *(const uint4*)&Vt[((size_t)(bh * 128 + r)) * 2048 + kv0 + c * 8];
    }
    for (int it = tid; it < 1024; it += 256) {
      int r = it >> 4, c = it & 15;
      *(float4*)&sims[r][c * 4] =
          *(const float4*)&sim[((size_t)(b * 2048) + qt * 64 + r) * 2048 + kv0 + c * 4];
    }
    if (tid < 64) mskf[tid] = npm[b * 2048 + kv0 + tid];
    __syncthreads();

    f32x4 sc[4];
    #pragma unroll
    for (int tt = 0; tt < 4; ++tt) {
      sc[tt] = (f32x4){0.f, 0.f, 0.f, 0.f};
      #pragma unroll
      for (int kc = 0; kc < 4; ++kc) {
        bf16x8 kf = *(bf16x8*)&Ks[tt * 16 + l16][kc * 32 + lh * 8];
        sc[tt] = __builtin_amdgcn_mfma_f32_16x16x32_bf16(qf[kc], kf, sc[tt], 0, 0, 0);
      }
    }
    float sv[4][4];
    #pragma unroll
    for (int tt = 0; tt < 4; ++tt) {
      int kvl = tt * 16 + l16;
      int kvg = kv0 + kvl;
      float msk = mskf[kvl];
      #pragma unroll
      for (int r = 0; r < 4; ++r) {
        int qg = q0 + lh * 4 + r;
        bool valid = (kvg <= qg) && (msk != 0.f);
        sv[tt][r] = valid
            ? sc[tt][r] * 0.08838834764831845f + sims[w * 16 + lh * 4 + r][kvl]
            : -1e9f;
      }
    }
    #pragma unroll
    for (int r = 0; r < 4; ++r) {
      float mx = fmaxf(fmaxf(sv[0][r], sv[1][r]), fmaxf(sv[2][r], sv[3][r]));
      mx = fmaxf(mx, __shfl_xor(mx, 1));
      mx = fmaxf(mx, __shfl_xor(mx, 2));
      mx = fmaxf(mx, __shfl_xor(mx, 4));
      mx = fmaxf(mx, __shfl_xor(mx, 8));
      float mn = fmaxf(m_r[r], mx);
      float alpha = __expf(m_r[r] - mn);
      m_r[r] = mn;
      float ts = 0.f;
      #pragma unroll
      for (int tt = 0; tt < 4; ++tt) {
        float p = __expf(sv[tt][r] - mn);
        sv[tt][r] = p;
        ts += p;
      }
      ts += __shfl_xor(ts, 1);
      ts += __shfl_xor(ts, 2);
      ts += __shfl_xor(ts, 4);
      ts += __shfl_xor(ts, 8);
      l_r[r] = l_r[r] * alpha + ts;
      #pragma unroll
      for (int c = 0; c < 8; ++c) o_acc[c][r] *= alpha;
    }
    #pragma unroll
    for (int tt = 0; tt < 4; ++tt)
      #pragma unroll
      for (int r = 0; r < 4; ++r)
        Pl[w][lh * 4 + r][tt * 16 + l16] = f2bf(sv[tt][r]);
    #pragma unroll
    for (int kf2 = 0; kf2 < 2; ++kf2) {
      bf16x8 pa = *(bf16x8*)&Pl[w][l16][kf2 * 32 + lh * 8];
      #pragma unroll
      for (int c = 0; c < 8; ++c) {
        bf16x8 vf = *(bf16x8*)&Vts[c * 16 + l16][kf2 * 32 + lh * 8];
        o_acc[c] = __builtin_amdgcn_mfma_f32_16x16x32_bf16(pa, vf, o_acc[c], 0, 0, 0);
      }
    }
  }
  #pragma unroll
  for (int r = 0; r < 4; ++r) {
    float inv = 1.f / l_r[r];
    int qg = q0 + lh * 4 + r;
    unsigned short* op = O + ((size_t)(b * 2048 + qg)) * 512 + h * 128;
    #pragma unroll
    for (int c = 0; c < 8; ++c) op[c * 16 + l16] = f2bf(o_acc[c][r] * inv);
  }
}

// ---------------- layernorm (+ optional bf16 copy) ----------------
__global__ __launch_bounds__(256) void ln_kernel(
    const float* __restrict__ x, const float* __restrict__ res,
    const float* __restrict__ g, const float* __restrict__ bta,
    const float* __restrict__ npm, float* __restrict__ out,
    unsigned short* __restrict__ out16) {
  __shared__ float ssum[4], ssq[4];
  int row = blockIdx.x;
  int tid = threadIdx.x;
  size_t base = (size_t)row * DM_;
  float v0 = x[base + tid] + res[base + tid];
  float v1 = x[base + tid + 256] + res[base + tid + 256];
  float sum = v0 + v1, sq = v0 * v0 + v1 * v1;
  #pragma unroll
  for (int off = 32; off >= 1; off >>= 1) {
    sum += __shfl_down(sum, off);
    sq += __shfl_down(sq, off);
  }
  int wid = tid >> 6, lane = tid & 63;
  if (lane == 0) { ssum[wid] = sum; ssq[wid] = sq; }
  __syncthreads();
  sum = ssum[0] + ssum[1] + ssum[2] + ssum[3];
  sq = ssq[0] + ssq[1] + ssq[2] + ssq[3];
  float mean = sum * (1.f / DM_);
  float var = sq * (1.f / DM_) - mean * mean;
  float rs = rsqrtf(var + 1e-5f);
  float mask = npm[row];
  float o0 = ((v0 - mean) * rs * g[tid] + bta[tid]) * mask;
  float o1 = ((v1 - mean) * rs * g[tid + 256] + bta[tid + 256]) * mask;
  out[base + tid] = o0;
  out[base + tid + 256] = o1;
  if (out16) {
    out16[base + tid] = f2bf(o0);
    out16[base + tid + 256] = f2bf(o1);
  }
}

extern "C" void kernel_launch(void* const* d_in, const int* in_sizes, int n_in,
                              void* d_out, int out_size, void* d_ws,
                              size_t ws_size, hipStream_t stream) {
  const int* et = (const int*)d_in[0];
  const int* vx = (const int*)d_in[1];
  const float* tmv = (const float*)d_in[2];
  const float* npm = (const float*)d_in[3];
  const float* Amat = (const float*)d_in[4];
  const float* Wmat = (const float*)d_in[5];
  const float* eemb = (const float*)d_in[6];
  const float* vemb = (const float*)d_in[7];
  const float* Wq = (const float*)d_in[8];
  const float* Wk = (const float*)d_in[9];
  const float* Wv = (const float*)d_in[10];
  const float* Wo = (const float*)d_in[11];
  const float* bo = (const float*)d_in[12];
  const float* ln1g = (const float*)d_in[13];
  const float* ln1b = (const float*)d_in[14];
  const float* w1 = (const float*)d_in[15];
  const float* b1 = (const float*)d_in[16];
  const float* w2 = (const float*)d_in[17];
  const float* b2 = (const float*)d_in[18];
  const float* ln2g = (const float*)d_in[19];
  const float* ln2b = (const float*)d_in[20];

  float* out = (float*)d_out;
  float* enc_out = out;
  float* sim_out = out + (size_t)B_ * S_ * DM_;

  const size_t MB = 1ull << 20;
  char* wsb = (char*)d_ws;
  float* enc0 = (float*)(wsb + 0);                        // 16MB, live to LN1
  unsigned short* enc0b = (unsigned short*)(wsb + 16 * MB);   // 8MB, dead after QKV
  unsigned short* WqT = (unsigned short*)(wsb + 24 * MB);     // 0.5MB each
  unsigned short* WkT = WqT + 512 * 512;
  unsigned short* WvT = WkT + 512 * 512;
  unsigned short* WoT = WvT + 512 * 512;
  unsigned short* w1T = WoT + 512 * 512;                       // [1024][512] 1MB
  unsigned short* w2T = w1T + 1024 * 512;                      // [512][1024] 1MB
  unsigned short* Qb16 = (unsigned short*)(wsb + 28 * MB);     // 8MB
  unsigned short* Kb16 = (unsigned short*)(wsb + 36 * MB);     // 8MB
  unsigned short* Vt16 = (unsigned short*)(wsb + 44 * MB);     // 8MB
  unsigned short* Of16 = (unsigned short*)(wsb + 52 * MB);     // 8MB
  float* OP = (float*)(wsb + 60 * MB);                         // 16MB
  float* enc1 = OP;                                            // in-place LN1
  unsigned short* enc1b = (unsigned short*)(wsb + 16 * MB);    // reuse enc0b slot
  unsigned short* hid = (unsigned short*)(wsb + 28 * MB);      // 16MB over Qb16+Kb16
  float* fbuf = (float*)(wsb + 44 * MB);                       // 16MB over Vt16+Of16
  float* AW = (float*)(wsb + 76 * MB);                         // 100MB optional
  bool use_aw = ws_size >= 76 * MB + (size_t)NV_ * NV_ * 4;

  int M = B_ * S_;

  embed_kernel<<<dim3(M), dim3(256), 0, stream>>>(et, vx, tmv, npm, eemb, vemb,
                                                  enc0, enc0b);
  if (use_aw) {
    aw_kernel<<<dim3(4096), dim3(256), 0, stream>>>(Amat, Wmat, AW);
    sim2_kernel<<<dim3(S_, B_), dim3(256), 0, stream>>>(vx, AW, sim_out);
  } else {
    sim_kernel<<<dim3(S_, B_), dim3(256), 0, stream>>>(vx, Amat, Wmat, sim_out);
  }

  wt_kernel<<<dim3(16, 16), dim3(256), 0, stream>>>(Wq, WqT, 512, 512);
  wt_kernel<<<dim3(16, 16), dim3(256), 0, stream>>>(Wk, WkT, 512, 512);
  wt_kernel<<<dim3(16, 16), dim3(256), 0, stream>>>(Wv, WvT, 512, 512);
  wt_kernel<<<dim3(16, 16), dim3(256), 0, stream>>>(Wo, WoT, 512, 512);
  wt_kernel<<<dim3(32, 16), dim3(256), 0, stream>>>(w1, w1T, 512, 1024);
  wt_kernel<<<dim3(16, 32), dim3(256), 0, stream>>>(w2, w2T, 1024, 512);

  gemm_bf16_kernel<2, false><<<dim3(4, 64), dim3(256), 0, stream>>>(
      enc0b, WqT, nullptr, Qb16, M, DM_, DM_);
  gemm_bf16_kernel<2, false><<<dim3(4, 64), dim3(256), 0, stream>>>(
      enc0b, WkT, nullptr, Kb16, M, DM_, DM_);
  gemm_bf16_kernel<3, false><<<dim3(4, 64), dim3(256), 0, stream>>>(
      enc0b, WvT, nullptr, Vt16, M, DM_, DM_);

  attn_mfma_kernel<<<dim3(512), dim3(256), 0, stream>>>(
      Qb16, Kb16, Vt16, sim_out, npm, Of16);

  gemm_bf16_kernel<0, false><<<dim3(4, 64), dim3(256), 0, stream>>>(
      Of16, WoT, bo, OP, M, DM_, DM_);
  ln_kernel<<<dim3(M), dim3(256), 0, stream>>>(OP, enc0, ln1g, ln1b, npm, enc1,
                                               enc1b);

  gemm_bf16_kernel<1, true><<<dim3(8, 64), dim3(256), 0, stream>>>(
      enc1b, w1T, b1, hid, M, DI_, DM_);
  gemm_bf16_kernel<0, false><<<dim3(4, 64), dim3(256), 0, stream>>>(
      hid, w2T, b2, fbuf, M, DM_, DI_);
  ln_kernel<<<dim3(M), dim3(256), 0, stream>>>(fbuf, enc1, ln2g, ln2b, npm,
                                               enc_out, nullptr);
}

// Round 7
// 412.997 us; speedup vs baseline: 5.6573x; 1.2476x over previous
//
#include <hip/hip_runtime.h>
#include <hip/hip_bf16.h>

#define B_ 4
#define S_ 2048
#define DM_ 512
#define H_ 4
#define DK_ 128
#define DI_ 1024
#define NV_ 5000

typedef __attribute__((ext_vector_type(8))) short bf16x8;
typedef __attribute__((ext_vector_type(8))) unsigned short u16x8;
typedef __attribute__((ext_vector_type(4))) unsigned short u16x4;
typedef __attribute__((ext_vector_type(4))) float f32x4;

__device__ inline unsigned short f2bf(float x) {
  unsigned int u = __float_as_uint(x);
  unsigned int r = (u + 0x7fffu + ((u >> 16) & 1u)) >> 16;
  return (unsigned short)r;
}

// ---------------- embed + temporal (f32 + bf16 outputs) ----------------
__global__ __launch_bounds__(256) void embed_kernel(
    const int* __restrict__ et, const int* __restrict__ vx,
    const float* __restrict__ tmv, const float* __restrict__ npm,
    const float* __restrict__ eemb, const float* __restrict__ vemb,
    float* __restrict__ enc0, unsigned short* __restrict__ enc0b) {
  int row = blockIdx.x;
  int t = et[row], v = vx[row];
  float time = tmv[row], mask = npm[row];
  int tid = threadIdx.x;
  #pragma unroll
  for (int k = 0; k < 2; ++k) {
    int dd = tid + k * 256;
    float pv = powf(10000.0f, (float)(dd & ~1) / 512.0f);
    float r = time / pv;
    float tem = (((dd & 1) == 0) ? sinf(r) : cosf(r)) * mask;
    float val = eemb[(size_t)t * DM_ + dd] + vemb[(size_t)v * DM_ + dd] + tem;
    enc0[(size_t)row * DM_ + dd] = val;
    enc0b[(size_t)row * DM_ + dd] = f2bf(val);
  }
}

// ---------------- similarity: stage A,W rows in LDS, gather ----------------
__global__ __launch_bounds__(256) void sim_kernel(
    const int* __restrict__ vx, const float* __restrict__ A,
    const float* __restrict__ W, float* __restrict__ sim) {
  __shared__ float Ar[NV_];
  __shared__ float Wr[NV_];
  int i = blockIdx.x;
  int b = blockIdx.y;
  int vi = vx[b * S_ + i];
  float* out = sim + ((size_t)(b * S_ + i)) * S_;
  int tid = threadIdx.x;
  if (vi == 0) {
    for (int j = tid * 4; j < S_; j += 1024)
      *(float4*)&out[j] = (float4){0.f, 0.f, 0.f, 0.f};
    return;
  }
  const float4* Arow = (const float4*)(A + (size_t)(vi - 1) * NV_);
  const float4* Wrow = (const float4*)(W + (size_t)(vi - 1) * NV_);
  for (int j = tid; j < NV_ / 4; j += 256) {
    ((float4*)Ar)[j] = Arow[j];
    ((float4*)Wr)[j] = Wrow[j];
  }
  __syncthreads();
  for (int j = tid * 4; j < S_; j += 1024) {
    int4 vj = *(const int4*)&vx[b * S_ + j];
    float4 o;
    o.x = vj.x ? Ar[vj.x - 1] * Wr[vj.x - 1] * 10.0f : 0.f;
    o.y = vj.y ? Ar[vj.y - 1] * Wr[vj.y - 1] * 10.0f : 0.f;
    o.z = vj.z ? Ar[vj.z - 1] * Wr[vj.z - 1] * 10.0f : 0.f;
    o.w = vj.w ? Ar[vj.w - 1] * Wr[vj.w - 1] * 10.0f : 0.f;
    *(float4*)&out[j] = o;
  }
}

// ---------------- weight transpose+cast: W[K][N] f32 -> WT[N][K] bf16 ----------------
__global__ __launch_bounds__(256) void wt_kernel(
    const float* __restrict__ W, unsigned short* __restrict__ WT,
    int K, int N) {
  __shared__ unsigned short T[32][40];
  int n0 = blockIdx.x * 32, k0 = blockIdx.y * 32;
  int r = threadIdx.x >> 3, c0 = (threadIdx.x & 7) * 4;
  float4 v = *(const float4*)&W[(size_t)(k0 + r) * N + n0 + c0];
  T[r][c0 + 0] = f2bf(v.x);
  T[r][c0 + 1] = f2bf(v.y);
  T[r][c0 + 2] = f2bf(v.z);
  T[r][c0 + 3] = f2bf(v.w);
  __syncthreads();
  u16x4 o;
  o[0] = T[c0 + 0][r]; o[1] = T[c0 + 1][r];
  o[2] = T[c0 + 2][r]; o[3] = T[c0 + 3][r];
  *(u16x4*)&WT[(size_t)(n0 + r) * K + k0 + c0] = o;
}

// ---------------- bf16 MFMA GEMM: C = A[M,K] @ BT[N,K]^T (+bias)(+relu) ----------------
// OMODE: 0 = f32 [M][N]; 1 = bf16 [M][N]; 2 = bf16 QK head-split; 3 = bf16 V-transposed
template <int OMODE, bool RELU>
__global__ __launch_bounds__(256) void gemm_bf16_kernel(
    const unsigned short* __restrict__ A, const unsigned short* __restrict__ BT,
    const float* __restrict__ bias, void* __restrict__ C,
    int M, int N, int K) {
  __shared__ __attribute__((aligned(16))) unsigned short As[128][72];
  __shared__ __attribute__((aligned(16))) unsigned short Bs[128][72];
  int tid = threadIdx.x;
  int w = tid >> 6, l = tid & 63;
  int l16 = l & 15, lh = l >> 4;
  int wr = w >> 1, wc = w & 1;
  int row0 = blockIdx.y * 128, col0 = blockIdx.x * 128;
  int ra = tid >> 1, ha = (tid & 1) * 32;
  f32x4 acc[4][4];
  #pragma unroll
  for (int m = 0; m < 4; ++m)
    #pragma unroll
    for (int n = 0; n < 4; ++n) acc[m][n] = (f32x4){0.f, 0.f, 0.f, 0.f};

  for (int k0 = 0; k0 < K; k0 += 64) {
    __syncthreads();
    {
      const unsigned short* sa = &A[(size_t)(row0 + ra) * K + k0 + ha];
      uint4 a0 = *(const uint4*)(sa);
      uint4 a1 = *(const uint4*)(sa + 8);
      uint4 a2 = *(const uint4*)(sa + 16);
      uint4 a3 = *(const uint4*)(sa + 24);
      *(uint4*)&As[ra][ha + 0] = a0;
      *(uint4*)&As[ra][ha + 8] = a1;
      *(uint4*)&As[ra][ha + 16] = a2;
      *(uint4*)&As[ra][ha + 24] = a3;
      const unsigned short* sb = &BT[(size_t)(col0 + ra) * K + k0 + ha];
      uint4 b0 = *(const uint4*)(sb);
      uint4 b1 = *(const uint4*)(sb + 8);
      uint4 b2 = *(const uint4*)(sb + 16);
      uint4 b3 = *(const uint4*)(sb + 24);
      *(uint4*)&Bs[ra][ha + 0] = b0;
      *(uint4*)&Bs[ra][ha + 8] = b1;
      *(uint4*)&Bs[ra][ha + 16] = b2;
      *(uint4*)&Bs[ra][ha + 24] = b3;
    }
    __syncthreads();
    #pragma unroll
    for (int kc = 0; kc < 2; ++kc) {
      bf16x8 af[4], bfr[4];
      #pragma unroll
      for (int m = 0; m < 4; ++m)
        af[m] = *(bf16x8*)&As[wr * 64 + m * 16 + l16][kc * 32 + lh * 8];
      #pragma unroll
      for (int n = 0; n < 4; ++n)
        bfr[n] = *(bf16x8*)&Bs[wc * 64 + n * 16 + l16][kc * 32 + lh * 8];
      #pragma unroll
      for (int m = 0; m < 4; ++m)
        #pragma unroll
        for (int n = 0; n < 4; ++n)
          acc[m][n] = __builtin_amdgcn_mfma_f32_16x16x32_bf16(af[m], bfr[n], acc[m][n], 0, 0, 0);
    }
  }
  #pragma unroll
  for (int m = 0; m < 4; ++m) {
    #pragma unroll
    for (int r = 0; r < 4; ++r) {
      int row = row0 + wr * 64 + m * 16 + lh * 4 + r;
      #pragma unroll
      for (int n = 0; n < 4; ++n) {
        int colg = col0 + wc * 64 + n * 16 + l16;
        float v = acc[m][n][r];
        if (bias) v += bias[colg];
        if (RELU) v = fmaxf(v, 0.f);
        if (OMODE == 0) {
          ((float*)C)[(size_t)row * N + colg] = v;
        } else if (OMODE == 1) {
          ((unsigned short*)C)[(size_t)row * N + colg] = f2bf(v);
        } else if (OMODE == 2) {
          int b = row >> 11, s = row & 2047;
          int h = colg >> 7, d = colg & 127;
          ((unsigned short*)C)[((size_t)((b * 4 + h) * 2048 + s)) * 128 + d] = f2bf(v);
        } else {
          int b = row >> 11, s = row & 2047;
          int h = colg >> 7, d = colg & 127;
          ((unsigned short*)C)[((size_t)((b * 4 + h) * 128 + d)) * 2048 + s] = f2bf(v);
        }
      }
    }
  }
}

// ---------------- MFMA flash attention: paired q-tiles, double-buffered ----------------
// grid = (16 pairs, 16 bh); block = 256 (4 waves); uniform 33 kv-steps per block
__global__ __launch_bounds__(256) void attn_mfma_kernel(
    const unsigned short* __restrict__ Qb, const unsigned short* __restrict__ Kb,
    const unsigned short* __restrict__ Vt, const float* __restrict__ sim,
    const float* __restrict__ npm, unsigned short* __restrict__ O) {
  __shared__ __attribute__((aligned(16))) unsigned short Ks[2][64][136];
  __shared__ __attribute__((aligned(16))) unsigned short Vts[2][128][72];
  __shared__ __attribute__((aligned(16))) unsigned short Pl[4][16][72];
  int pair = blockIdx.x;   // 0..15
  int bh = blockIdx.y;     // b*H + h
  int b = bh >> 2;
  int h = bh & 3;
  int tid = threadIdx.x;
  int w = tid >> 6, l = tid & 63;
  int l16 = l & 15, lh = l >> 4;
  int kr = tid >> 4, kc = tid & 15;   // K staging: rows kr+{0,16,32,48}
  int vr = tid >> 3, vc = tid & 7;    // V staging: rows vr+{0,32,64,96}

  uint4 kg[4], vg[4];
  auto stage_load = [&](int kv0) {
    const unsigned short* kp = Kb + ((size_t)(bh * 2048 + kv0 + kr)) * 128 + kc * 8;
    kg[0] = *(const uint4*)(kp);
    kg[1] = *(const uint4*)(kp + 16 * 128);
    kg[2] = *(const uint4*)(kp + 32 * 128);
    kg[3] = *(const uint4*)(kp + 48 * 128);
    const unsigned short* vp = Vt + ((size_t)(bh * 128 + vr)) * 2048 + kv0 + vc * 8;
    vg[0] = *(const uint4*)(vp);
    vg[1] = *(const uint4*)(vp + 32 * 2048);
    vg[2] = *(const uint4*)(vp + 64 * 2048);
    vg[3] = *(const uint4*)(vp + 96 * 2048);
  };
  auto stage_write = [&](int bi) {
    *(uint4*)&Ks[bi][kr][kc * 8] = kg[0];
    *(uint4*)&Ks[bi][kr + 16][kc * 8] = kg[1];
    *(uint4*)&Ks[bi][kr + 32][kc * 8] = kg[2];
    *(uint4*)&Ks[bi][kr + 48][kc * 8] = kg[3];
    *(uint4*)&Vts[bi][vr][vc * 8] = vg[0];
    *(uint4*)&Vts[bi][vr + 32][vc * 8] = vg[1];
    *(uint4*)&Vts[bi][vr + 64][vc * 8] = vg[2];
    *(uint4*)&Vts[bi][vr + 96][vc * 8] = vg[3];
  };

  #pragma unroll 1
  for (int pi = 0; pi < 2; ++pi) {
    int qt = pi ? 31 - pair : pair;
    int nst = qt + 1;
    int q0 = qt * 64 + w * 16;

    bf16x8 qf[4];
    const unsigned short* Qrow = Qb + ((size_t)(bh * 2048 + q0 + l16)) * 128;
    #pragma unroll
    for (int kq = 0; kq < 4; ++kq)
      qf[kq] = *(const bf16x8*)&Qrow[kq * 32 + lh * 8];

    float m_r[4], l_r[4];
    f32x4 o_acc[8];
    #pragma unroll
    for (int r = 0; r < 4; ++r) { m_r[r] = -INFINITY; l_r[r] = 0.f; }
    #pragma unroll
    for (int c = 0; c < 8; ++c) o_acc[c] = (f32x4){0.f, 0.f, 0.f, 0.f};

    stage_load(0);
    stage_write(0);
    __syncthreads();

    #pragma unroll 1
    for (int t = 0; t < nst; ++t) {
      int cur = t & 1;
      int kv0 = t * 64;
      if (t + 1 < nst) stage_load((t + 1) * 64);

      // direct sim/npm loads (L3-resident), in flight during QK MFMAs
      float simv[4][4], mskv[4];
      #pragma unroll
      for (int tt = 0; tt < 4; ++tt) {
        int kvg = kv0 + tt * 16 + l16;
        mskv[tt] = npm[b * 2048 + kvg];
        #pragma unroll
        for (int r = 0; r < 4; ++r) {
          int qg = q0 + lh * 4 + r;
          simv[tt][r] = sim[((size_t)(b * 2048) + qg) * 2048 + kvg];
        }
      }

      f32x4 sc[4];
      #pragma unroll
      for (int tt = 0; tt < 4; ++tt) {
        sc[tt] = (f32x4){0.f, 0.f, 0.f, 0.f};
        #pragma unroll
        for (int kq = 0; kq < 4; ++kq) {
          bf16x8 kf = *(bf16x8*)&Ks[cur][tt * 16 + l16][kq * 32 + lh * 8];
          sc[tt] = __builtin_amdgcn_mfma_f32_16x16x32_bf16(qf[kq], kf, sc[tt], 0, 0, 0);
        }
      }
      float sv[4][4];
      #pragma unroll
      for (int tt = 0; tt < 4; ++tt) {
        int kvg = kv0 + tt * 16 + l16;
        bool kvalid = (mskv[tt] != 0.f);
        #pragma unroll
        for (int r = 0; r < 4; ++r) {
          int qg = q0 + lh * 4 + r;
          bool valid = (kvg <= qg) && kvalid;
          sv[tt][r] = valid ? sc[tt][r] * 0.08838834764831845f + simv[tt][r]
                            : -1e9f;
        }
      }
      #pragma unroll
      for (int r = 0; r < 4; ++r) {
        float mx = fmaxf(fmaxf(sv[0][r], sv[1][r]), fmaxf(sv[2][r], sv[3][r]));
        mx = fmaxf(mx, __shfl_xor(mx, 1));
        mx = fmaxf(mx, __shfl_xor(mx, 2));
        mx = fmaxf(mx, __shfl_xor(mx, 4));
        mx = fmaxf(mx, __shfl_xor(mx, 8));
        float mn = fmaxf(m_r[r], mx);
        float alpha = __expf(m_r[r] - mn);
        m_r[r] = mn;
        float ts = 0.f;
        #pragma unroll
        for (int tt = 0; tt < 4; ++tt) {
          float p = __expf(sv[tt][r] - mn);
          sv[tt][r] = p;
          ts += p;
        }
        ts += __shfl_xor(ts, 1);
        ts += __shfl_xor(ts, 2);
        ts += __shfl_xor(ts, 4);
        ts += __shfl_xor(ts, 8);
        l_r[r] = l_r[r] * alpha + ts;
        #pragma unroll
        for (int c = 0; c < 8; ++c) o_acc[c][r] *= alpha;
      }
      #pragma unroll
      for (int tt = 0; tt < 4; ++tt)
        #pragma unroll
        for (int r = 0; r < 4; ++r)
          Pl[w][lh * 4 + r][tt * 16 + l16] = f2bf(sv[tt][r]);
      #pragma unroll
      for (int kf2 = 0; kf2 < 2; ++kf2) {
        bf16x8 pa = *(bf16x8*)&Pl[w][l16][kf2 * 32 + lh * 8];
        #pragma unroll
        for (int c = 0; c < 8; ++c) {
          bf16x8 vf = *(bf16x8*)&Vts[cur][c * 16 + l16][kf2 * 32 + lh * 8];
          o_acc[c] = __builtin_amdgcn_mfma_f32_16x16x32_bf16(pa, vf, o_acc[c], 0, 0, 0);
        }
      }
      __syncthreads();
      if (t + 1 < nst) {
        stage_write((t + 1) & 1);
        __syncthreads();
      }
    }
    // epilogue
    #pragma unroll
    for (int r = 0; r < 4; ++r) {
      float inv = 1.f / l_r[r];
      int qg = q0 + lh * 4 + r;
      unsigned short* op = O + ((size_t)(b * 2048 + qg)) * 512 + h * 128;
      #pragma unroll
      for (int c = 0; c < 8; ++c) op[c * 16 + l16] = f2bf(o_acc[c][r] * inv);
    }
  }
}

// ---------------- layernorm (+ optional bf16 copy) ----------------
__global__ __launch_bounds__(256) void ln_kernel(
    const float* __restrict__ x, const float* __restrict__ res,
    const float* __restrict__ g, const float* __restrict__ bta,
    const float* __restrict__ npm, float* __restrict__ out,
    unsigned short* __restrict__ out16) {
  __shared__ float ssum[4], ssq[4];
  int row = blockIdx.x;
  int tid = threadIdx.x;
  size_t base = (size_t)row * DM_;
  float v0 = x[base + tid] + res[base + tid];
  float v1 = x[base + tid + 256] + res[base + tid + 256];
  float sum = v0 + v1, sq = v0 * v0 + v1 * v1;
  #pragma unroll
  for (int off = 32; off >= 1; off >>= 1) {
    sum += __shfl_down(sum, off);
    sq += __shfl_down(sq, off);
  }
  int wid = tid >> 6, lane = tid & 63;
  if (lane == 0) { ssum[wid] = sum; ssq[wid] = sq; }
  __syncthreads();
  sum = ssum[0] + ssum[1] + ssum[2] + ssum[3];
  sq = ssq[0] + ssq[1] + ssq[2] + ssq[3];
  float mean = sum * (1.f / DM_);
  float var = sq * (1.f / DM_) - mean * mean;
  float rs = rsqrtf(var + 1e-5f);
  float mask = npm[row];
  float o0 = ((v0 - mean) * rs * g[tid] + bta[tid]) * mask;
  float o1 = ((v1 - mean) * rs * g[tid + 256] + bta[tid + 256]) * mask;
  out[base + tid] = o0;
  out[base + tid + 256] = o1;
  if (out16) {
    out16[base + tid] = f2bf(o0);
    out16[base + tid + 256] = f2bf(o1);
  }
}

extern "C" void kernel_launch(void* const* d_in, const int* in_sizes, int n_in,
                              void* d_out, int out_size, void* d_ws,
                              size_t ws_size, hipStream_t stream) {
  const int* et = (const int*)d_in[0];
  const int* vx = (const int*)d_in[1];
  const float* tmv = (const float*)d_in[2];
  const float* npm = (const float*)d_in[3];
  const float* Amat = (const float*)d_in[4];
  const float* Wmat = (const float*)d_in[5];
  const float* eemb = (const float*)d_in[6];
  const float* vemb = (const float*)d_in[7];
  const float* Wq = (const float*)d_in[8];
  const float* Wk = (const float*)d_in[9];
  const float* Wv = (const float*)d_in[10];
  const float* Wo = (const float*)d_in[11];
  const float* bo = (const float*)d_in[12];
  const float* ln1g = (const float*)d_in[13];
  const float* ln1b = (const float*)d_in[14];
  const float* w1 = (const float*)d_in[15];
  const float* b1 = (const float*)d_in[16];
  const float* w2 = (const float*)d_in[17];
  const float* b2 = (const float*)d_in[18];
  const float* ln2g = (const float*)d_in[19];
  const float* ln2b = (const float*)d_in[20];

  float* out = (float*)d_out;
  float* enc_out = out;
  float* sim_out = out + (size_t)B_ * S_ * DM_;

  const size_t MB = 1ull << 20;
  char* wsb = (char*)d_ws;
  float* enc0 = (float*)(wsb + 0);                             // 16MB, live to LN1
  unsigned short* enc0b = (unsigned short*)(wsb + 16 * MB);    // 8MB
  unsigned short* WqT = (unsigned short*)(wsb + 24 * MB);
  unsigned short* WkT = WqT + 512 * 512;
  unsigned short* WvT = WkT + 512 * 512;
  unsigned short* WoT = WvT + 512 * 512;
  unsigned short* w1T = WoT + 512 * 512;
  unsigned short* w2T = w1T + 1024 * 512;
  unsigned short* Qb16 = (unsigned short*)(wsb + 28 * MB);
  unsigned short* Kb16 = (unsigned short*)(wsb + 36 * MB);
  unsigned short* Vt16 = (unsigned short*)(wsb + 44 * MB);
  unsigned short* Of16 = (unsigned short*)(wsb + 52 * MB);
  float* OP = (float*)(wsb + 60 * MB);
  float* enc1 = OP;
  unsigned short* enc1b = (unsigned short*)(wsb + 16 * MB);
  unsigned short* hid = (unsigned short*)(wsb + 28 * MB);
  float* fbuf = (float*)(wsb + 44 * MB);

  int M = B_ * S_;

  embed_kernel<<<dim3(M), dim3(256), 0, stream>>>(et, vx, tmv, npm, eemb, vemb,
                                                  enc0, enc0b);
  sim_kernel<<<dim3(S_, B_), dim3(256), 0, stream>>>(vx, Amat, Wmat, sim_out);

  wt_kernel<<<dim3(16, 16), dim3(256), 0, stream>>>(Wq, WqT, 512, 512);
  wt_kernel<<<dim3(16, 16), dim3(256), 0, stream>>>(Wk, WkT, 512, 512);
  wt_kernel<<<dim3(16, 16), dim3(256), 0, stream>>>(Wv, WvT, 512, 512);
  wt_kernel<<<dim3(16, 16), dim3(256), 0, stream>>>(Wo, WoT, 512, 512);
  wt_kernel<<<dim3(32, 16), dim3(256), 0, stream>>>(w1, w1T, 512, 1024);
  wt_kernel<<<dim3(16, 32), dim3(256), 0, stream>>>(w2, w2T, 1024, 512);

  gemm_bf16_kernel<2, false><<<dim3(4, 64), dim3(256), 0, stream>>>(
      enc0b, WqT, nullptr, Qb16, M, DM_, DM_);
  gemm_bf16_kernel<2, false><<<dim3(4, 64), dim3(256), 0, stream>>>(
      enc0b, WkT, nullptr, Kb16, M, DM_, DM_);
  gemm_bf16_kernel<3, false><<<dim3(4, 64), dim3(256), 0, stream>>>(
      enc0b, WvT, nullptr, Vt16, M, DM_, DM_);

  attn_mfma_kernel<<<dim3(16, 16), dim3(256), 0, stream>>>(
      Qb16, Kb16, Vt16, sim_out, npm, Of16);

  gemm_bf16_kernel<0, false><<<dim3(4, 64), dim3(256), 0, stream>>>(
      Of16, WoT, bo, OP, M, DM_, DM_);
  ln_kernel<<<dim3(M), dim3(256), 0, stream>>>(OP, enc0, ln1g, ln1b, npm, enc1,
                                               enc1b);

  gemm_bf16_kernel<1, true><<<dim3(8, 64), dim3(256), 0, stream>>>(
      enc1b, w1T, b1, hid, M, DI_, DM_);
  gemm_bf16_kernel<0, false><<<dim3(4, 64), dim3(256), 0, stream>>>(
      hid, w2T, b2, fbuf, M, DM_, DI_);
  ln_kernel<<<dim3(M), dim3(256), 0, stream>>>(fbuf, enc1, ln2g, ln2b, npm,
                                               enc_out, nullptr);
}

// Round 8
// 405.506 us; speedup vs baseline: 5.7618x; 1.0185x over previous
//
#include <hip/hip_runtime.h>
#include <hip/hip_bf16.h>

#define B_ 4
#define S_ 2048
#define DM_ 512
#define H_ 4
#define DK_ 128
#define DI_ 1024
#define NV_ 5000

typedef __attribute__((ext_vector_type(8))) short bf16x8;
typedef __attribute__((ext_vector_type(8))) unsigned short u16x8;
typedef __attribute__((ext_vector_type(4))) unsigned short u16x4;
typedef __attribute__((ext_vector_type(4))) float f32x4;

__device__ inline unsigned short f2bf(float x) {
  unsigned int u = __float_as_uint(x);
  unsigned int r = (u + 0x7fffu + ((u >> 16) & 1u)) >> 16;
  return (unsigned short)r;
}

// ---------------- embed + temporal (f32 + bf16 outputs) ----------------
__global__ __launch_bounds__(256) void embed_kernel(
    const int* __restrict__ et, const int* __restrict__ vx,
    const float* __restrict__ tmv, const float* __restrict__ npm,
    const float* __restrict__ eemb, const float* __restrict__ vemb,
    float* __restrict__ enc0, unsigned short* __restrict__ enc0b) {
  int row = blockIdx.x;
  int t = et[row], v = vx[row];
  float time = tmv[row], mask = npm[row];
  int tid = threadIdx.x;
  #pragma unroll
  for (int k = 0; k < 2; ++k) {
    int dd = tid + k * 256;
    float pv = powf(10000.0f, (float)(dd & ~1) / 512.0f);
    float r = time / pv;
    float tem = (((dd & 1) == 0) ? sinf(r) : cosf(r)) * mask;
    float val = eemb[(size_t)t * DM_ + dd] + vemb[(size_t)v * DM_ + dd] + tem;
    enc0[(size_t)row * DM_ + dd] = val;
    enc0b[(size_t)row * DM_ + dd] = f2bf(val);
  }
}

// ---------------- similarity: stage A,W rows in LDS, gather ----------------
__global__ __launch_bounds__(256) void sim_kernel(
    const int* __restrict__ vx, const float* __restrict__ A,
    const float* __restrict__ W, float* __restrict__ sim) {
  __shared__ float Ar[NV_];
  __shared__ float Wr[NV_];
  int i = blockIdx.x;
  int b = blockIdx.y;
  int vi = vx[b * S_ + i];
  float* out = sim + ((size_t)(b * S_ + i)) * S_;
  int tid = threadIdx.x;
  if (vi == 0) {
    for (int j = tid * 4; j < S_; j += 1024)
      *(float4*)&out[j] = (float4){0.f, 0.f, 0.f, 0.f};
    return;
  }
  const float4* Arow = (const float4*)(A + (size_t)(vi - 1) * NV_);
  const float4* Wrow = (const float4*)(W + (size_t)(vi - 1) * NV_);
  for (int j = tid; j < NV_ / 4; j += 256) {
    ((float4*)Ar)[j] = Arow[j];
    ((float4*)Wr)[j] = Wrow[j];
  }
  __syncthreads();
  for (int j = tid * 4; j < S_; j += 1024) {
    int4 vj = *(const int4*)&vx[b * S_ + j];
    float4 o;
    o.x = vj.x ? Ar[vj.x - 1] * Wr[vj.x - 1] * 10.0f : 0.f;
    o.y = vj.y ? Ar[vj.y - 1] * Wr[vj.y - 1] * 10.0f : 0.f;
    o.z = vj.z ? Ar[vj.z - 1] * Wr[vj.z - 1] * 10.0f : 0.f;
    o.w = vj.w ? Ar[vj.w - 1] * Wr[vj.w - 1] * 10.0f : 0.f;
    *(float4*)&out[j] = o;
  }
}

// ---------------- weight transpose+cast: W[K][N] f32 -> WT[N][K] bf16 ----------------
__global__ __launch_bounds__(256) void wt_kernel(
    const float* __restrict__ W, unsigned short* __restrict__ WT,
    int K, int N) {
  __shared__ unsigned short T[32][40];
  int n0 = blockIdx.x * 32, k0 = blockIdx.y * 32;
  int r = threadIdx.x >> 3, c0 = (threadIdx.x & 7) * 4;
  float4 v = *(const float4*)&W[(size_t)(k0 + r) * N + n0 + c0];
  T[r][c0 + 0] = f2bf(v.x);
  T[r][c0 + 1] = f2bf(v.y);
  T[r][c0 + 2] = f2bf(v.z);
  T[r][c0 + 3] = f2bf(v.w);
  __syncthreads();
  u16x4 o;
  o[0] = T[c0 + 0][r]; o[1] = T[c0 + 1][r];
  o[2] = T[c0 + 2][r]; o[3] = T[c0 + 3][r];
  *(u16x4*)&WT[(size_t)(n0 + r) * K + k0 + c0] = o;
}

// ---------------- bf16 MFMA GEMM: C = A[M,K] @ BT[N,K]^T (+bias)(+relu) ----------------
// OMODE: 0 = f32 [M][N]; 1 = bf16 [M][N]; 2 = bf16 QK head-split; 3 = bf16 V-transposed
template <int OMODE, bool RELU>
__global__ __launch_bounds__(256) void gemm_bf16_kernel(
    const unsigned short* __restrict__ A, const unsigned short* __restrict__ BT,
    const float* __restrict__ bias, void* __restrict__ C,
    int M, int N, int K) {
  __shared__ __attribute__((aligned(16))) unsigned short As[128][72];
  __shared__ __attribute__((aligned(16))) unsigned short Bs[128][72];
  int tid = threadIdx.x;
  int w = tid >> 6, l = tid & 63;
  int l16 = l & 15, lh = l >> 4;
  int wr = w >> 1, wc = w & 1;
  int row0 = blockIdx.y * 128, col0 = blockIdx.x * 128;
  int ra = tid >> 1, ha = (tid & 1) * 32;
  f32x4 acc[4][4];
  #pragma unroll
  for (int m = 0; m < 4; ++m)
    #pragma unroll
    for (int n = 0; n < 4; ++n) acc[m][n] = (f32x4){0.f, 0.f, 0.f, 0.f};

  for (int k0 = 0; k0 < K; k0 += 64) {
    __syncthreads();
    {
      const unsigned short* sa = &A[(size_t)(row0 + ra) * K + k0 + ha];
      uint4 a0 = *(const uint4*)(sa);
      uint4 a1 = *(const uint4*)(sa + 8);
      uint4 a2 = *(const uint4*)(sa + 16);
      uint4 a3 = *(const uint4*)(sa + 24);
      *(uint4*)&As[ra][ha + 0] = a0;
      *(uint4*)&As[ra][ha + 8] = a1;
      *(uint4*)&As[ra][ha + 16] = a2;
      *(uint4*)&As[ra][ha + 24] = a3;
      const unsigned short* sb = &BT[(size_t)(col0 + ra) * K + k0 + ha];
      uint4 b0 = *(const uint4*)(sb);
      uint4 b1 = *(const uint4*)(sb + 8);
      uint4 b2 = *(const uint4*)(sb + 16);
      uint4 b3 = *(const uint4*)(sb + 24);
      *(uint4*)&Bs[ra][ha + 0] = b0;
      *(uint4*)&Bs[ra][ha + 8] = b1;
      *(uint4*)&Bs[ra][ha + 16] = b2;
      *(uint4*)&Bs[ra][ha + 24] = b3;
    }
    __syncthreads();
    #pragma unroll
    for (int kc = 0; kc < 2; ++kc) {
      bf16x8 af[4], bfr[4];
      #pragma unroll
      for (int m = 0; m < 4; ++m)
        af[m] = *(bf16x8*)&As[wr * 64 + m * 16 + l16][kc * 32 + lh * 8];
      #pragma unroll
      for (int n = 0; n < 4; ++n)
        bfr[n] = *(bf16x8*)&Bs[wc * 64 + n * 16 + l16][kc * 32 + lh * 8];
      #pragma unroll
      for (int m = 0; m < 4; ++m)
        #pragma unroll
        for (int n = 0; n < 4; ++n)
          acc[m][n] = __builtin_amdgcn_mfma_f32_16x16x32_bf16(af[m], bfr[n], acc[m][n], 0, 0, 0);
    }
  }
  #pragma unroll
  for (int m = 0; m < 4; ++m) {
    #pragma unroll
    for (int r = 0; r < 4; ++r) {
      int row = row0 + wr * 64 + m * 16 + lh * 4 + r;
      #pragma unroll
      for (int n = 0; n < 4; ++n) {
        int colg = col0 + wc * 64 + n * 16 + l16;
        float v = acc[m][n][r];
        if (bias) v += bias[colg];
        if (RELU) v = fmaxf(v, 0.f);
        if (OMODE == 0) {
          ((float*)C)[(size_t)row * N + colg] = v;
        } else if (OMODE == 1) {
          ((unsigned short*)C)[(size_t)row * N + colg] = f2bf(v);
        } else if (OMODE == 2) {
          int b = row >> 11, s = row & 2047;
          int h = colg >> 7, d = colg & 127;
          ((unsigned short*)C)[((size_t)((b * 4 + h) * 2048 + s)) * 128 + d] = f2bf(v);
        } else {
          int b = row >> 11, s = row & 2047;
          int h = colg >> 7, d = colg & 127;
          ((unsigned short*)C)[((size_t)((b * 4 + h) * 128 + d)) * 2048 + s] = f2bf(v);
        }
      }
    }
  }
}

// ---------------- MFMA flash attention: swapped QK^T, single-buffer, paired tiles ----
// grid = (16 pairs, 16 bh); block = 256 (4 waves); uniform 33 kv-steps per block
__global__ __launch_bounds__(256) void attn_mfma_kernel(
    const unsigned short* __restrict__ Qb, const unsigned short* __restrict__ Kb,
    const unsigned short* __restrict__ Vt, const float* __restrict__ sim,
    const float* __restrict__ npm, unsigned short* __restrict__ O) {
  __shared__ __attribute__((aligned(16))) unsigned short Ks[64][136];
  __shared__ __attribute__((aligned(16))) unsigned short Vts[128][72];
  __shared__ __attribute__((aligned(16))) unsigned short Pl[4][16][72];
  int pair = blockIdx.x;   // 0..15
  int bh = blockIdx.y;     // b*H + h
  int b = bh >> 2;
  int h = bh & 3;
  int tid = threadIdx.x;
  int w = tid >> 6, l = tid & 63;
  int l16 = l & 15, lh = l >> 4;
  int kr = tid >> 4, kc = tid & 15;   // K staging: rows kr+{0,16,32,48}
  int vr = tid >> 3, vc = tid & 7;    // V staging: rows vr+{0,32,64,96}

  uint4 kg[4], vg[4];
  auto stage_load = [&](int kv0) {
    const unsigned short* kp = Kb + ((size_t)(bh * 2048 + kv0 + kr)) * 128 + kc * 8;
    kg[0] = *(const uint4*)(kp);
    kg[1] = *(const uint4*)(kp + 16 * 128);
    kg[2] = *(const uint4*)(kp + 32 * 128);
    kg[3] = *(const uint4*)(kp + 48 * 128);
    const unsigned short* vp = Vt + ((size_t)(bh * 128 + vr)) * 2048 + kv0 + vc * 8;
    vg[0] = *(const uint4*)(vp);
    vg[1] = *(const uint4*)(vp + 32 * 2048);
    vg[2] = *(const uint4*)(vp + 64 * 2048);
    vg[3] = *(const uint4*)(vp + 96 * 2048);
  };
  auto stage_write = [&]() {
    *(uint4*)&Ks[kr][kc * 8] = kg[0];
    *(uint4*)&Ks[kr + 16][kc * 8] = kg[1];
    *(uint4*)&Ks[kr + 32][kc * 8] = kg[2];
    *(uint4*)&Ks[kr + 48][kc * 8] = kg[3];
    *(uint4*)&Vts[vr][vc * 8] = vg[0];
    *(uint4*)&Vts[vr + 32][vc * 8] = vg[1];
    *(uint4*)&Vts[vr + 64][vc * 8] = vg[2];
    *(uint4*)&Vts[vr + 96][vc * 8] = vg[3];
  };

  #pragma unroll 1
  for (int pi = 0; pi < 2; ++pi) {
    int qt = pi ? 31 - pair : pair;
    int nst = qt + 1;
    int q0 = qt * 64 + w * 16;
    int qg = q0 + l16;   // this lane's q row (swapped layout)

    bf16x8 qf[4];
    const unsigned short* Qrow = Qb + ((size_t)(bh * 2048 + qg)) * 128;
    #pragma unroll
    for (int kq = 0; kq < 4; ++kq)
      qf[kq] = *(const bf16x8*)&Qrow[kq * 32 + lh * 8];

    float m_l = -INFINITY, l_l = 0.f;   // per-lane running max/sum for q = qg
    f32x4 o_acc[8];
    #pragma unroll
    for (int c = 0; c < 8; ++c) o_acc[c] = (f32x4){0.f, 0.f, 0.f, 0.f};

    stage_load(0);
    stage_write();
    __syncthreads();

    #pragma unroll 1
    for (int t = 0; t < nst; ++t) {
      int kv0 = t * 64;
      if (t + 1 < nst) stage_load(kv0 + 64);

      // direct sim/npm loads (L2/L3-resident), in flight during QK MFMAs
      float simv[4][4];
      float4 mk4[4];
      #pragma unroll
      for (int tt = 0; tt < 4; ++tt) {
        mk4[tt] = *(const float4*)&npm[b * 2048 + kv0 + tt * 16 + lh * 4];
        #pragma unroll
        for (int r = 0; r < 4; ++r)
          simv[tt][r] =
              sim[((size_t)(b * 2048) + qg) * 2048 + kv0 + tt * 16 + lh * 4 + r];
      }

      // swapped QK^T: C col = q (l16), row = kv (lh*4+r)
      f32x4 sc[4];
      #pragma unroll
      for (int tt = 0; tt < 4; ++tt) {
        sc[tt] = (f32x4){0.f, 0.f, 0.f, 0.f};
        #pragma unroll
        for (int kq = 0; kq < 4; ++kq) {
          bf16x8 kf = *(bf16x8*)&Ks[tt * 16 + l16][kq * 32 + lh * 8];
          sc[tt] = __builtin_amdgcn_mfma_f32_16x16x32_bf16(kf, qf[kq], sc[tt], 0, 0, 0);
        }
      }
      float sv[4][4];
      #pragma unroll
      for (int tt = 0; tt < 4; ++tt) {
        #pragma unroll
        for (int r = 0; r < 4; ++r) {
          int kvg = kv0 + tt * 16 + lh * 4 + r;
          float mkr = r == 0 ? mk4[tt].x : r == 1 ? mk4[tt].y : r == 2 ? mk4[tt].z : mk4[tt].w;
          bool valid = (kvg <= qg) && (mkr != 0.f);
          sv[tt][r] = valid ? sc[tt][r] * 0.08838834764831845f + simv[tt][r]
                            : -1e9f;
        }
      }
      // online softmax: lane owns full row slice; reduce in-lane + xor16/xor32
      float mx = sv[0][0];
      #pragma unroll
      for (int tt = 0; tt < 4; ++tt)
        #pragma unroll
        for (int r = 0; r < 4; ++r) mx = fmaxf(mx, sv[tt][r]);
      mx = fmaxf(mx, __shfl_xor(mx, 16));
      mx = fmaxf(mx, __shfl_xor(mx, 32));
      float mn = fmaxf(m_l, mx);
      float alpha = __expf(m_l - mn);
      m_l = mn;
      float ts = 0.f;
      #pragma unroll
      for (int tt = 0; tt < 4; ++tt)
        #pragma unroll
        for (int r = 0; r < 4; ++r) {
          float p = __expf(sv[tt][r] - mn);
          sv[tt][r] = p;
          ts += p;
        }
      ts += __shfl_xor(ts, 16);
      ts += __shfl_xor(ts, 32);
      l_l = l_l * alpha + ts;
      // P write: row q = l16, kv contiguous per tt -> ushort4
      #pragma unroll
      for (int tt = 0; tt < 4; ++tt) {
        u16x4 pw;
        pw[0] = f2bf(sv[tt][0]); pw[1] = f2bf(sv[tt][1]);
        pw[2] = f2bf(sv[tt][2]); pw[3] = f2bf(sv[tt][3]);
        *(u16x4*)&Pl[w][l16][tt * 16 + lh * 4] = pw;
      }
      // rescale O rows (q = lh*4+r): alpha from lane l16 = lh*4+r
      float al[4];
      #pragma unroll
      for (int r = 0; r < 4; ++r) al[r] = __shfl(alpha, lh * 4 + r);
      #pragma unroll
      for (int c = 0; c < 8; ++c)
        #pragma unroll
        for (int r = 0; r < 4; ++r) o_acc[c][r] *= al[r];
      // PV
      #pragma unroll
      for (int kf2 = 0; kf2 < 2; ++kf2) {
        bf16x8 pa = *(bf16x8*)&Pl[w][l16][kf2 * 32 + lh * 8];
        #pragma unroll
        for (int c = 0; c < 8; ++c) {
          bf16x8 vf = *(bf16x8*)&Vts[c * 16 + l16][kf2 * 32 + lh * 8];
          o_acc[c] = __builtin_amdgcn_mfma_f32_16x16x32_bf16(pa, vf, o_acc[c], 0, 0, 0);
        }
      }
      __syncthreads();
      if (t + 1 < nst) {
        stage_write();
        __syncthreads();
      }
    }
    // epilogue: O row q = lh*4+r, l from lane l16 = lh*4+r
    float linv[4];
    #pragma unroll
    for (int r = 0; r < 4; ++r) {
      float lv = __shfl(l_l, lh * 4 + r);
      linv[r] = 1.f / lv;
    }
    #pragma unroll
    for (int r = 0; r < 4; ++r) {
      int qgr = q0 + lh * 4 + r;
      unsigned short* op = O + ((size_t)(b * 2048 + qgr)) * 512 + h * 128;
      #pragma unroll
      for (int c = 0; c < 8; ++c) op[c * 16 + l16] = f2bf(o_acc[c][r] * linv[r]);
    }
  }
}

// ---------------- layernorm (+ optional bf16 copy) ----------------
__global__ __launch_bounds__(256) void ln_kernel(
    const float* __restrict__ x, const float* __restrict__ res,
    const float* __restrict__ g, const float* __restrict__ bta,
    const float* __restrict__ npm, float* __restrict__ out,
    unsigned short* __restrict__ out16) {
  __shared__ float ssum[4], ssq[4];
  int row = blockIdx.x;
  int tid = threadIdx.x;
  size_t base = (size_t)row * DM_;
  float v0 = x[base + tid] + res[base + tid];
  float v1 = x[base + tid + 256] + res[base + tid + 256];
  float sum = v0 + v1, sq = v0 * v0 + v1 * v1;
  #pragma unroll
  for (int off = 32; off >= 1; off >>= 1) {
    sum += __shfl_down(sum, off);
    sq += __shfl_down(sq, off);
  }
  int wid = tid >> 6, lane = tid & 63;
  if (lane == 0) { ssum[wid] = sum; ssq[wid] = sq; }
  __syncthreads();
  sum = ssum[0] + ssum[1] + ssum[2] + ssum[3];
  sq = ssq[0] + ssq[1] + ssq[2] + ssq[3];
  float mean = sum * (1.f / DM_);
  float var = sq * (1.f / DM_) - mean * mean;
  float rs = rsqrtf(var + 1e-5f);
  float mask = npm[row];
  float o0 = ((v0 - mean) * rs * g[tid] + bta[tid]) * mask;
  float o1 = ((v1 - mean) * rs * g[tid + 256] + bta[tid + 256]) * mask;
  out[base + tid] = o0;
  out[base + tid + 256] = o1;
  if (out16) {
    out16[base + tid] = f2bf(o0);
    out16[base + tid + 256] = f2bf(o1);
  }
}

extern "C" void kernel_launch(void* const* d_in, const int* in_sizes, int n_in,
                              void* d_out, int out_size, void* d_ws,
                              size_t ws_size, hipStream_t stream) {
  const int* et = (const int*)d_in[0];
  const int* vx = (const int*)d_in[1];
  const float* tmv = (const float*)d_in[2];
  const float* npm = (const float*)d_in[3];
  const float* Amat = (const float*)d_in[4];
  const float* Wmat = (const float*)d_in[5];
  const float* eemb = (const float*)d_in[6];
  const float* vemb = (const float*)d_in[7];
  const float* Wq = (const float*)d_in[8];
  const float* Wk = (const float*)d_in[9];
  const float* Wv = (const float*)d_in[10];
  const float* Wo = (const float*)d_in[11];
  const float* bo = (const float*)d_in[12];
  const float* ln1g = (const float*)d_in[13];
  const float* ln1b = (const float*)d_in[14];
  const float* w1 = (const float*)d_in[15];
  const float* b1 = (const float*)d_in[16];
  const float* w2 = (const float*)d_in[17];
  const float* b2 = (const float*)d_in[18];
  const float* ln2g = (const float*)d_in[19];
  const float* ln2b = (const float*)d_in[20];

  float* out = (float*)d_out;
  float* enc_out = out;
  float* sim_out = out + (size_t)B_ * S_ * DM_;

  const size_t MB = 1ull << 20;
  char* wsb = (char*)d_ws;
  float* enc0 = (float*)(wsb + 0);                             // 16MB, live to LN1
  unsigned short* enc0b = (unsigned short*)(wsb + 16 * MB);    // 8MB
  unsigned short* WqT = (unsigned short*)(wsb + 24 * MB);
  unsigned short* WkT = WqT + 512 * 512;
  unsigned short* WvT = WkT + 512 * 512;
  unsigned short* WoT = WvT + 512 * 512;
  unsigned short* w1T = WoT + 512 * 512;
  unsigned short* w2T = w1T + 1024 * 512;
  unsigned short* Qb16 = (unsigned short*)(wsb + 28 * MB);
  unsigned short* Kb16 = (unsigned short*)(wsb + 36 * MB);
  unsigned short* Vt16 = (unsigned short*)(wsb + 44 * MB);
  unsigned short* Of16 = (unsigned short*)(wsb + 52 * MB);
  float* OP = (float*)(wsb + 60 * MB);
  float* enc1 = OP;
  unsigned short* enc1b = (unsigned short*)(wsb + 16 * MB);
  unsigned short* hid = (unsigned short*)(wsb + 28 * MB);
  float* fbuf = (float*)(wsb + 44 * MB);

  int M = B_ * S_;

  embed_kernel<<<dim3(M), dim3(256), 0, stream>>>(et, vx, tmv, npm, eemb, vemb,
                                                  enc0, enc0b);
  sim_kernel<<<dim3(S_, B_), dim3(256), 0, stream>>>(vx, Amat, Wmat, sim_out);

  wt_kernel<<<dim3(16, 16), dim3(256), 0, stream>>>(Wq, WqT, 512, 512);
  wt_kernel<<<dim3(16, 16), dim3(256), 0, stream>>>(Wk, WkT, 512, 512);
  wt_kernel<<<dim3(16, 16), dim3(256), 0, stream>>>(Wv, WvT, 512, 512);
  wt_kernel<<<dim3(16, 16), dim3(256), 0, stream>>>(Wo, WoT, 512, 512);
  wt_kernel<<<dim3(32, 16), dim3(256), 0, stream>>>(w1, w1T, 512, 1024);
  wt_kernel<<<dim3(16, 32), dim3(256), 0, stream>>>(w2, w2T, 1024, 512);

  gemm_bf16_kernel<2, false><<<dim3(4, 64), dim3(256), 0, stream>>>(
      enc0b, WqT, nullptr, Qb16, M, DM_, DM_);
  gemm_bf16_kernel<2, false><<<dim3(4, 64), dim3(256), 0, stream>>>(
      enc0b, WkT, nullptr, Kb16, M, DM_, DM_);
  gemm_bf16_kernel<3, false><<<dim3(4, 64), dim3(256), 0, stream>>>(
      enc0b, WvT, nullptr, Vt16, M, DM_, DM_);

  attn_mfma_kernel<<<dim3(16, 16), dim3(256), 0, stream>>>(
      Qb16, Kb16, Vt16, sim_out, npm, Of16);

  gemm_bf16_kernel<0, false><<<dim3(4, 64), dim3(256), 0, stream>>>(
      Of16, WoT, bo, OP, M, DM_, DM_);
  ln_kernel<<<dim3(M), dim3(256), 0, stream>>>(OP, enc0, ln1g, ln1b, npm, enc1,
                                               enc1b);

  gemm_bf16_kernel<1, true><<<dim3(8, 64), dim3(256), 0, stream>>>(
      enc1b, w1T, b1, hid, M, DI_, DM_);
  gemm_bf16_kernel<0, false><<<dim3(4, 64), dim3(256), 0, stream>>>(
      hid, w2T, b2, fbuf, M, DM_, DI_);
  ln_kernel<<<dim3(M), dim3(256), 0, stream>>>(fbuf, enc1, ln2g, ln2b, npm,
                                               enc_out, nullptr);
}